// Round 15
// baseline (481.616 us; speedup 1.0000x reference)
//
#include <hip/hip_runtime.h>
#include <hip/hip_bf16.h>

typedef __hip_bfloat16 bf16;
using short8  = __attribute__((ext_vector_type(8))) short;
using floatx4 = __attribute__((ext_vector_type(4))) float;

__device__ __forceinline__ float b2f(unsigned short u) {
    union { unsigned int i; float f; } v; v.i = ((unsigned int)u) << 16; return v.f;
}
__device__ __forceinline__ unsigned short f2b(float f) {
    bf16 h = __float2bfloat16(f);
    return *(unsigned short*)&h;
}

// ---------------------------------------------------------------------------
// Workspace layout (bytes) — NON-OVERLAPPING:
//   dynk  @ 0        : fp32 (k1 6144 | k2T 131072 | k3T 147456 | k4T 524288 | k5T 262144 els)
//   stats @ 4284416  : 30720 fp32, 16 replicas per layer -> ends 4407296
//   WT    @ 4407296  : bf16 -> ends 5275648
//   S1    @ 5308416  : bf16 y1/y2/y3/y4 -> ends 72417280
//   S2    @ 72417280 : bf16 A2/A3/A4/A5 -> ends 89194496
//   aff   @ 89194496 : 1920 fp32 BN affine | cnts @ 89202176 : 4 u32
//
// r14 lesson: bn_prep 1-block launches cost pure latency; folded into the
// LAST finishing block of each stats producer (counter + threadfence +
// atomic-read pattern; stats atomics are device-scope).
// ---------------------------------------------------------------------------
#define NREP 16

__global__ __launch_bounds__(256) void prep_kernel(
    const int* __restrict__ label, const float* __restrict__ emb,
    const float* __restrict__ l1w, const float* __restrict__ l1b,
    const float* __restrict__ l2w, const float* __restrict__ l2b,
    const float* __restrict__ l3w, const float* __restrict__ l3b,
    const float* __restrict__ l4w, const float* __restrict__ l4b,
    const float* __restrict__ l5w, const float* __restrict__ l5b,
    float* __restrict__ dynk, float* __restrict__ stats,
    unsigned* __restrict__ cnts, float* __restrict__ labelOut)
{
    const int tid = threadIdx.x;
    if (blockIdx.x == gridDim.x - 1) {                   // housekeeping block
        for (int i = tid; i < 30720; i += 256) stats[i] = 0.0f;
        if (tid < 4) cnts[tid] = 0u;
        if (tid < 128) labelOut[tid] = (float)label[tid];
        return;
    }
    int idx = blockIdx.x * 256 + tid;
    if (idx >= 1071104) return;
    const float* w; const float* bb; int loc, ckk, ksk, base;
    if (idx < 6144)        { w = l1w; bb = l1b; loc = idx;          ckk = 48;   ksk = 0;  base = 0;      }
    else if (idx < 137216) { w = l2w; bb = l2b; loc = idx - 6144;   ckk = 1024; ksk = 16; base = 6144;   }
    else if (idx < 284672) { w = l3w; bb = l3b; loc = idx - 137216; ckk = 1152; ksk = 9;  base = 137216; }
    else if (idx < 808960) { w = l4w; bb = l4b; loc = idx - 284672; ckk = 4096; ksk = 16; base = 284672; }
    else                   { w = l5w; bb = l5b; loc = idx - 808960; ckk = 2048; ksk = 4;  base = 808960; }
    int b   = loc / ckk;
    int col = loc - b * ckk;
    int lab = label[b];
    float acc = bb[col];
    #pragma unroll
    for (int m = 0; m < 5; ++m)
        acc = fmaf(emb[lab * 5 + m], w[m * ckk + col], acc);
    float val = tanhf(acc);
    if (ksk == 0) {
        dynk[idx] = val;                          // layer 1: [b][c*k*k]
    } else {
        int c  = col / ksk;                       // transposed: [b][tap][c]
        int t  = col - c * ksk;
        int Cl = ckk / ksk;
        dynk[base + b * ckk + t * Cl + c] = val;
    }
}

// transpose-convert channel-mix weights: WT[n][k] = bf16(W[k][n]), layers 2..5
__global__ __launch_bounds__(256) void wt_kernel(
    const float* __restrict__ w2, const float* __restrict__ w3,
    const float* __restrict__ w4, const float* __restrict__ w5,
    bf16* __restrict__ wt2, bf16* __restrict__ wt3,
    bf16* __restrict__ wt4, bf16* __restrict__ wt5)
{
    __shared__ float T[32][33];
    const int tid = threadIdx.x;
    int t = blockIdx.x;
    const float* W; bf16* WT; int K, N, tl;
    if (t < 8)        { W = w2; WT = wt2; K = 64;  N = 128; tl = t; }
    else if (t < 40)  { W = w3; WT = wt3; K = 128; N = 256; tl = t - 8; }
    else if (t < 168) { W = w4; WT = wt4; K = 256; N = 512; tl = t - 40; }
    else              { W = w5; WT = wt5; K = 512; N = 512; tl = t - 168; }
    const int NT = N >> 5;
    const int kt = tl / NT, nt = tl - kt * NT;
    const int k0 = kt * 32, n0 = nt * 32;
    const int cc = tid & 31, rr = tid >> 5;
    #pragma unroll
    for (int it = 0; it < 4; ++it) {
        int k = rr + it * 8;
        T[k][cc] = W[(long)(k0 + k) * N + n0 + cc];
    }
    __syncthreads();
    #pragma unroll
    for (int it = 0; it < 4; ++it) {
        int n = rr + it * 8;
        WT[(long)(n0 + n) * K + k0 + cc] = __float2bfloat16(T[cc][n]);
    }
}

// ---------------------------------------------------------------------------
// Layer 1 v4: 16w x 8h tile per block, 128 threads, 4096 blocks.
// Staging is a fixed 15-slot fully-unrolled predicated loop -> compiler
// batches all 15 loads per thread (r14: runtime-trip loop kept ~1 in flight).
// Last finishing block computes aff1 (bn fold, counter pattern).
// ---------------------------------------------------------------------------
__global__ __launch_bounds__(128) void fused_l1_v4(
    const float* __restrict__ xf, const float* __restrict__ dynk,
    const float* __restrict__ W, const float* __restrict__ bias,
    bf16* __restrict__ y, float* __restrict__ statsOut,
    const float* __restrict__ gam, const float* __restrict__ bet,
    float* __restrict__ aff, unsigned* __restrict__ cnt, int nblk)
{
    constexpr int HIN = 128, HOUT = 64;
    constexpr int TW = 16, TH = 8;
    constexpr int PS  = 36;
    constexpr int PCH = 18 * PS;

    __shared__ float patch[3 * PCH];
    __shared__ __align__(16) float dwT[16 * 28];
    __shared__ float Wlds[192];
    __shared__ float klds[48];
    __shared__ float biasL[64];
    __shared__ float sums[64], sqs[64];
    __shared__ int lastFlag;

    const int tid = threadIdx.x;
    const int b   = blockIdx.x >> 5;
    const int tl  = blockIdx.x & 31;
    const int ty0 = (tl >> 2) * TH;
    const int tx0 = (tl & 3) * TW;

    if (tid < 48) klds[tid] = dynk[b * 48 + tid];
    for (int i = tid; i < 192; i += 128) Wlds[i] = W[i];
    if (tid < 64) { biasL[tid] = bias[tid]; sums[tid] = 0.f; sqs[tid] = 0.f; }

    {   // stage padded patch: 1836 floats, 15 fixed slots/thread, batched loads
        const int iy0 = ty0 * 2 - 1, ix0 = tx0 * 2 - 1;
        #pragma unroll
        for (int k = 0; k < 15; ++k) {
            int i  = tid + k * 128;
            int c  = i / 612;
            int r  = i - c * 612;
            int py = r / 34, px = r - py * 34;
            int gy = iy0 + py, gx = ix0 + px;
            bool slot = (i < 1836);
            bool inb  = slot && ((unsigned)gy < (unsigned)HIN) && ((unsigned)gx < (unsigned)HIN);
            float v = 0.f;
            if (inb) v = xf[((long)b * 3 + c) * (HIN * HIN) + gy * HIN + gx];
            if (slot) patch[c * PCH + py * PS + px] = v;
        }
    }
    __syncthreads();

    {   // depthwise conv: thread = pixel
        const int py = tid >> 4, px = tid & 15;
        const int pixg = tid >> 3, j = tid & 7;
        #pragma unroll
        for (int c = 0; c < 3; ++c) {
            const float* pb = &patch[c * PCH + (py * 2) * PS + px * 2];
            float a = 0.f;
            #pragma unroll
            for (int kh = 0; kh < 4; ++kh)
                #pragma unroll
                for (int kw = 0; kw < 4; ++kw)
                    a = fmaf(pb[kh * PS + kw], klds[c * 16 + kh * 4 + kw], a);
            dwT[pixg * 28 + j * 3 + c] = a;
        }
    }
    __syncthreads();

    {   // mix + lrelu + stats + coalesced store
        const int cq = tid & 7, pixg = tid >> 3;
        const int d0 = cq * 8;
        float Wr[3][8], bi[8];
        #pragma unroll
        for (int c = 0; c < 3; ++c)
            #pragma unroll
            for (int t = 0; t < 8; ++t) Wr[c][t] = Wlds[c * 64 + d0 + t];
        #pragma unroll
        for (int t = 0; t < 8; ++t) bi[t] = biasL[d0 + t];

        float dv[24];
        #pragma unroll
        for (int q4 = 0; q4 < 6; ++q4)
            *(float4*)&dv[q4 * 4] = *(const float4*)&dwT[pixg * 28 + q4 * 4];

        float sreg[8] = {}, qreg[8] = {};
        #pragma unroll
        for (int j = 0; j < 8; ++j) {
            const int pos = pixg * 8 + j;
            const float dv0 = dv[j * 3 + 0];
            const float dv1 = dv[j * 3 + 1];
            const float dv2 = dv[j * 3 + 2];
            const int py = pos >> 4, px = pos & 15;
            const long row = ((long)(b * HOUT + ty0 + py)) * HOUT + tx0 + px;
            union { uint4 v; unsigned short us[8]; } pk;
            #pragma unroll
            for (int t = 0; t < 8; ++t) {
                float v = fmaf(dv0, Wr[0][t], fmaf(dv1, Wr[1][t], fmaf(dv2, Wr[2][t], bi[t])));
                v = fmaxf(v, 0.2f * v);
                sreg[t] += v;
                qreg[t] = fmaf(v, v, qreg[t]);
                pk.us[t] = f2b(v);
            }
            *(uint4*)&y[row * 64 + d0] = pk.v;
        }
        #pragma unroll
        for (int m = 8; m < 64; m <<= 1)
            #pragma unroll
            for (int t = 0; t < 8; ++t) {
                sreg[t] += __shfl_xor(sreg[t], m);
                qreg[t] += __shfl_xor(qreg[t], m);
            }
        if ((tid & 63) < 8) {
            #pragma unroll
            for (int t = 0; t < 8; ++t) {
                atomicAdd(&sums[d0 + t], sreg[t]);
                atomicAdd(&sqs [d0 + t], qreg[t]);
            }
        }
    }
    __syncthreads();
    {
        const int rep = blockIdx.x & (NREP - 1);
        if (tid < 64) {
            atomicAdd(&statsOut[rep * 128 + tid],      sums[tid]);
            atomicAdd(&statsOut[rep * 128 + 64 + tid], sqs[tid]);
        }
    }
    __syncthreads();
    if (tid == 0) {
        __threadfence();
        unsigned old = atomicAdd(cnt, 1u);
        lastFlag = (old == (unsigned)(nblk - 1)) ? 1 : 0;
    }
    __syncthreads();
    if (lastFlag && tid < 64) {          // last block derives BN affine (C=64)
        const int c = tid;
        float s = 0.f, q = 0.f;
        #pragma unroll
        for (int r = 0; r < NREP; ++r) {
            s += atomicAdd(&statsOut[r * 128 + c], 0.0f);
            q += atomicAdd(&statsOut[r * 128 + 64 + c], 0.0f);
        }
        const float NINV = 1.f / 524288.f;
        float m   = s * NINV;
        float var = fmaf(q, NINV, -m * m);
        float sc  = gam[c] * rsqrtf(var + 1e-5f);
        aff[c]      = sc;
        aff[64 + c] = fmaf(-m, sc, bet[c]);
    }
}

// ---------------------------------------------------------------------------
// Direct-tap depthwise conv (layers 2..5): thread = (output pixel, 8 ch).
// ---------------------------------------------------------------------------
template<int C, int KS, int HIN, int HOUT, int STRIDE, int PAD, int NTHR>
__global__ __launch_bounds__(NTHR) void dw_direct(
    const bf16* __restrict__ x, const float* __restrict__ aff,
    const float* __restrict__ dynkT, bf16* __restrict__ outA)
{
    constexpr int G   = C / 8;
    constexpr int KSK = KS * KS;
    static_assert(NTHR == HOUT * G, "one output row per block");

    __shared__ __align__(16) float wlds[KSK * C];   // [tap][c], linear copy

    const int tid = threadIdx.x;
    const int b   = blockIdx.x / HOUT;
    const int oy  = blockIdx.x % HOUT;

    {
        const float* src = dynkT + (long)b * (KSK * C);
        for (int i = tid * 4; i < KSK * C; i += NTHR * 4)
            *(float4*)&wlds[i] = *(const float4*)&src[i];
    }
    __syncthreads();

    const int g  = tid % G;
    const int ox = tid / G;
    const int c0 = g * 8;
    const int iy0 = oy * STRIDE - PAD;
    const int ix0 = ox * STRIDE - PAD;

    float sc[8], sh[8];
    {
        float4 a0 = *(const float4*)&aff[c0];
        float4 a1 = *(const float4*)&aff[c0 + 4];
        float4 b0 = *(const float4*)&aff[C + c0];
        float4 b1 = *(const float4*)&aff[C + c0 + 4];
        sc[0]=a0.x; sc[1]=a0.y; sc[2]=a0.z; sc[3]=a0.w;
        sc[4]=a1.x; sc[5]=a1.y; sc[6]=a1.z; sc[7]=a1.w;
        sh[0]=b0.x; sh[1]=b0.y; sh[2]=b0.z; sh[3]=b0.w;
        sh[4]=b1.x; sh[5]=b1.y; sh[6]=b1.z; sh[7]=b1.w;
    }

    float acc[8];
    #pragma unroll
    for (int ch = 0; ch < 8; ++ch) acc[ch] = 0.f;

    const bool interior = (iy0 >= 0) && (iy0 + KS <= HIN) &&
                          (ix0 >= 0) && (ix0 + KS <= HIN);

    if (interior) {
        const bf16* bp = x + ((long)(b * HIN + iy0) * HIN + ix0) * C + c0;
        uint4 v[KSK];
        #pragma unroll
        for (int kh = 0; kh < KS; ++kh)
            #pragma unroll
            for (int kw = 0; kw < KS; ++kw)
                v[kh * KS + kw] = *(const uint4*)(bp + (kh * HIN + kw) * C);
        #pragma unroll
        for (int t = 0; t < KSK; ++t) {
            const float* wp = &wlds[t * C + c0];
            float4 wa = *(const float4*)wp;
            float4 wb = *(const float4*)(wp + 4);
            const float wt[8] = {wa.x, wa.y, wa.z, wa.w, wb.x, wb.y, wb.z, wb.w};
            #pragma unroll
            for (int ch = 0; ch < 8; ++ch) {
                unsigned u = ((const unsigned*)&v[t])[ch >> 1];
                unsigned bits = (ch & 1) ? (u & 0xffff0000u) : (u << 16);
                float xb = fmaf(__uint_as_float(bits), sc[ch], sh[ch]);
                acc[ch] = fmaf(xb, wt[ch], acc[ch]);
            }
        }
    } else {
        #pragma unroll
        for (int kh = 0; kh < KS; ++kh) {
            const int iy = iy0 + kh;
            if ((unsigned)iy >= (unsigned)HIN) continue;
            #pragma unroll
            for (int kw = 0; kw < KS; ++kw) {
                const int ix = ix0 + kw;
                if ((unsigned)ix >= (unsigned)HIN) continue;
                uint4 v = *(const uint4*)&x[((long)(b * HIN + iy) * HIN + ix) * C + c0];
                const float* wp = &wlds[(kh * KS + kw) * C + c0];
                float4 wa = *(const float4*)wp;
                float4 wb = *(const float4*)(wp + 4);
                const float wt[8] = {wa.x, wa.y, wa.z, wa.w, wb.x, wb.y, wb.z, wb.w};
                #pragma unroll
                for (int ch = 0; ch < 8; ++ch) {
                    unsigned u = ((const unsigned*)&v)[ch >> 1];
                    unsigned bits = (ch & 1) ? (u & 0xffff0000u) : (u << 16);
                    float xb = fmaf(__uint_as_float(bits), sc[ch], sh[ch]);
                    acc[ch] = fmaf(xb, wt[ch], acc[ch]);
                }
            }
        }
    }

    union { uint4 v; unsigned short us[8]; } pk;
    #pragma unroll
    for (int ch = 0; ch < 8; ++ch) pk.us[ch] = f2b(acc[ch]);
    *(uint4*)&outA[((long)(b * HOUT + oy) * HOUT + ox) * C + c0] = pk.v;
}

// ---------------------------------------------------------------------------
// MFMA bf16 GEMM, 128x128 tile, BK=64. Non-LAST: last finishing block also
// derives the next layer's BN affine (counter pattern, device-scope atomics).
// ---------------------------------------------------------------------------
template<int K, int COUT, bool LAST>
__global__ __launch_bounds__(256) void gemm_layer(
    const bf16* __restrict__ A, const bf16* __restrict__ WT,
    const float* __restrict__ bias, bf16* __restrict__ y,
    float* __restrict__ statsOut, float* __restrict__ outF, int Mtiles,
    const float* __restrict__ gam, const float* __restrict__ bet,
    float* __restrict__ aff, unsigned* __restrict__ cnt, float NINV, int nblk)
{
    constexpr int SK = 72;
    constexpr int CS = 136;
    __shared__ __align__(16) unsigned short smem[18432];
    unsigned short* As  = smem;
    unsigned short* Bs  = smem + 9216;
    unsigned short* Csh = smem;
    __shared__ float sums[128], sqs[128];
    __shared__ int lastFlag;

    const int tid  = threadIdx.x;
    const int lane = tid & 63;
    const int w    = tid >> 6;
    const int wm   = (w >> 1) * 64, wn = (w & 1) * 64;
    const int lm   = lane & 15, lq = lane >> 4;
    const int mt   = blockIdx.x % Mtiles;
    const int nt   = blockIdx.x / Mtiles;
    const long m0  = (long)mt * 128;
    const int  n0  = nt * 128;

    floatx4 acc[4][4];
    #pragma unroll
    for (int i = 0; i < 4; ++i)
        #pragma unroll
        for (int j = 0; j < 4; ++j) acc[i][j] = (floatx4)0.0f;

    for (int kb = 0; kb < K; kb += 64) {
        __syncthreads();
        #pragma unroll
        for (int s = 0; s < 4; ++s) {
            int i = tid + s * 256;
            int m = i >> 3, q = i & 7;
            uint4 va = *(const uint4*)(A  + ((m0 + m) * K + kb + q * 8));
            uint4 vb = *(const uint4*)(WT + ((long)(n0 + m) * K + kb + q * 8));
            *(uint4*)&As[m * SK + q * 8] = va;
            *(uint4*)&Bs[m * SK + q * 8] = vb;
        }
        __syncthreads();
        #pragma unroll
        for (int h = 0; h < 2; ++h) {
            short8 af[4], bfr[4];
            #pragma unroll
            for (int i = 0; i < 4; ++i) {
                af[i]  = *(const short8*)&As[(wm + i * 16 + lm) * SK + h * 32 + lq * 8];
                bfr[i] = *(const short8*)&Bs[(wn + i * 16 + lm) * SK + h * 32 + lq * 8];
            }
            #pragma unroll
            for (int i = 0; i < 4; ++i)
                #pragma unroll
                for (int j = 0; j < 4; ++j)
                    acc[i][j] = __builtin_amdgcn_mfma_f32_16x16x32_bf16(af[i], bfr[j], acc[i][j], 0, 0, 0);
        }
    }
    __syncthreads();

    float bj[4];
    #pragma unroll
    for (int j = 0; j < 4; ++j) bj[j] = bias[n0 + wn + j * 16 + lm];

    if constexpr (!LAST) {
        if (tid < 128) { sums[tid] = 0.f; sqs[tid] = 0.f; }
        #pragma unroll
        for (int i = 0; i < 4; ++i)
            #pragma unroll
            for (int j = 0; j < 4; ++j) {
                int c = wn + j * 16 + lm;
                #pragma unroll
                for (int rg = 0; rg < 4; ++rg) {
                    int r = wm + i * 16 + lq * 4 + rg;
                    float v = acc[i][j][rg] + bj[j];
                    v = fmaxf(v, 0.2f * v);
                    Csh[r * CS + c] = f2b(v);
                }
            }
        __syncthreads();
        const int cg = tid & 15, mr = tid >> 4;
        float sacc[8], qacc[8];
        #pragma unroll
        for (int t = 0; t < 8; ++t) { sacc[t] = 0.f; qacc[t] = 0.f; }
        #pragma unroll
        for (int it = 0; it < 8; ++it) {
            int m = mr + it * 16;
            uint4 pk = *(const uint4*)&Csh[m * CS + cg * 8];
            *(uint4*)&y[(m0 + m) * COUT + n0 + cg * 8] = pk;
            const unsigned short* pu = (const unsigned short*)&pk;
            #pragma unroll
            for (int t = 0; t < 8; ++t) {
                float f = b2f(pu[t]);
                sacc[t] += f;
                qacc[t] = fmaf(f, f, qacc[t]);
            }
        }
        #pragma unroll
        for (int t = 0; t < 8; ++t) {
            atomicAdd(&sums[cg * 8 + t], sacc[t]);
            atomicAdd(&sqs [cg * 8 + t], qacc[t]);
        }
        __syncthreads();
        {
            const int rep = blockIdx.x & (NREP - 1);
            if (tid < 128) {
                atomicAdd(&statsOut[rep * 2 * COUT + n0 + tid],        sums[tid]);
                atomicAdd(&statsOut[rep * 2 * COUT + COUT + n0 + tid], sqs[tid]);
            }
        }
        __syncthreads();
        if (tid == 0) {
            __threadfence();
            unsigned old = atomicAdd(cnt, 1u);
            lastFlag = (old == (unsigned)(nblk - 1)) ? 1 : 0;
        }
        __syncthreads();
        if (lastFlag) {
            for (int c = tid; c < COUT; c += 256) {
                float s = 0.f, q = 0.f;
                #pragma unroll
                for (int r = 0; r < NREP; ++r) {
                    s += atomicAdd(&statsOut[r * 2 * COUT + c], 0.0f);
                    q += atomicAdd(&statsOut[r * 2 * COUT + COUT + c], 0.0f);
                }
                float m   = s * NINV;
                float var = fmaf(q, NINV, -m * m);
                float sc  = gam[c] * rsqrtf(var + 1e-5f);
                aff[c]        = sc;
                aff[COUT + c] = fmaf(-m, sc, bet[c]);
            }
        }
    } else {
        #pragma unroll
        for (int i = 0; i < 4; ++i)
            #pragma unroll
            for (int j = 0; j < 4; ++j) {
                int c  = wn + j * 16 + lm;
                int rb = wm + i * 16 + lq * 4;
                ushort4 pk;
                unsigned short* pp = (unsigned short*)&pk;
                #pragma unroll
                for (int rg = 0; rg < 4; ++rg)
                    pp[rg] = f2b(acc[i][j][rg] + bj[j]);
                *(ushort4*)&Csh[c * CS + rb] = pk;
            }
        __syncthreads();
        const int mg = tid & 15, nr = tid >> 4;
        #pragma unroll
        for (int it = 0; it < 8; ++it) {
            int n = nr + it * 16;
            uint4 pk = *(const uint4*)&Csh[n * CS + mg * 8];
            const unsigned short* pu = (const unsigned short*)&pk;
            #pragma unroll
            for (int t = 0; t < 8; ++t) {
                int m = (int)m0 + mg * 8 + t;
                int b = m / 49, pos = m - b * 49;
                float v = b2f(pu[t]);
                outF[((long)(b * 512 + n0 + n)) * 49 + pos] = 1.f / (1.f + __expf(-v));
            }
        }
    }
}

// ---------------------------------------------------------------------------

extern "C" void kernel_launch(void* const* d_in, const int* in_sizes, int n_in,
                              void* d_out, int out_size, void* d_ws, size_t ws_size,
                              hipStream_t stream)
{
    const float* input = (const float*)d_in[0];
    const int*   label = (const int*)d_in[1];
    const float* emb   = (const float*)d_in[2];
    const float* lw[5] = {(const float*)d_in[3], (const float*)d_in[5], (const float*)d_in[7],
                          (const float*)d_in[9], (const float*)d_in[11]};
    const float* lb[5] = {(const float*)d_in[4], (const float*)d_in[6], (const float*)d_in[8],
                          (const float*)d_in[10], (const float*)d_in[12]};
    const float* cmw[5] = {(const float*)d_in[13], (const float*)d_in[15], (const float*)d_in[17],
                           (const float*)d_in[19], (const float*)d_in[21]};
    const float* cmb[5] = {(const float*)d_in[14], (const float*)d_in[16], (const float*)d_in[18],
                           (const float*)d_in[20], (const float*)d_in[22]};
    const float* bng[4] = {(const float*)d_in[23], (const float*)d_in[25],
                           (const float*)d_in[27], (const float*)d_in[29]};
    const float* bnb[4] = {(const float*)d_in[24], (const float*)d_in[26],
                           (const float*)d_in[28], (const float*)d_in[30]};
    float* out = (float*)d_out;

    float* wsf   = (float*)d_ws;
    float* dynk  = wsf;
    float* stats = wsf + 1071104;
    const float* k1  = dynk;
    const float* k2T = dynk + 6144;
    const float* k3T = dynk + 137216;
    const float* k4T = dynk + 284672;
    const float* k5T = dynk + 808960;
    float* st1 = stats;
    float* st2 = stats + 2048;
    float* st3 = stats + 6144;
    float* st4 = stats + 14336;

    bf16* wt  = (bf16*)((char*)d_ws + 4407296);
    bf16* wt2 = wt;
    bf16* wt3 = wt + 8192;
    bf16* wt4 = wt + 40960;
    bf16* wt5 = wt + 172032;
    bf16* S1  = (bf16*)((char*)d_ws + 5308416);
    bf16* S2  = (bf16*)((char*)d_ws + 72417280);
    float* affBase = (float*)((char*)d_ws + 89194496);
    float* aff1 = affBase;          // 128
    float* aff2 = affBase + 128;    // 256
    float* aff3 = affBase + 384;    // 512
    float* aff4 = affBase + 896;    // 1024
    unsigned* cnts = (unsigned*)((char*)d_ws + 89202176);

    prep_kernel<<<4186, 256, 0, stream>>>(label, emb,
        lw[0], lb[0], lw[1], lb[1], lw[2], lb[2], lw[3], lb[3], lw[4], lb[4],
        dynk, stats, cnts, out + 3211264);
    wt_kernel<<<424, 256, 0, stream>>>(cmw[1], cmw[2], cmw[3], cmw[4],
                                       wt2, wt3, wt4, wt5);

    // L1: fused (K=3) -> y1 + st1; last block derives aff1
    fused_l1_v4<<<4096, 128, 0, stream>>>(input, k1, cmw[0], cmb[0], S1, st1,
                                          bng[0], bnb[0], aff1, cnts + 0, 4096);

    // L2
    dw_direct<64, 4, 64, 32, 2, 1, 256><<<4096, 256, 0, stream>>>(S1, aff1, k2T, S2);
    gemm_layer<64, 128, false><<<1024, 256, 0, stream>>>(
        S2, wt2, cmb[1], S1, st2, nullptr, 1024,
        bng[1], bnb[1], aff2, cnts + 1, 1.f / 131072.f, 1024);

    // L3
    dw_direct<128, 3, 32, 16, 2, 1, 256><<<2048, 256, 0, stream>>>(S1, aff2, k3T, S2);
    gemm_layer<128, 256, false><<<512, 256, 0, stream>>>(
        S2, wt3, cmb[2], S1, st3, nullptr, 256,
        bng[2], bnb[2], aff3, cnts + 2, 1.f / 32768.f, 512);

    // L4
    dw_direct<256, 4, 16, 8, 2, 1, 256><<<1024, 256, 0, stream>>>(S1, aff3, k4T, S2);
    gemm_layer<256, 512, false><<<256, 256, 0, stream>>>(
        S2, wt4, cmb[3], S1, st4, nullptr, 64,
        bng[3], bnb[3], aff4, cnts + 3, 1.f / 8192.f, 256);

    // L5
    dw_direct<512, 2, 8, 7, 1, 0, 448><<<896, 448, 0, stream>>>(S1, aff4, k5T, S2);
    gemm_layer<512, 512, true><<<196, 256, 0, stream>>>(
        S2, wt5, cmb[4], nullptr, nullptr, out, 49,
        nullptr, nullptr, nullptr, nullptr, 0.f, 0);
}

// Round 16
// 327.536 us; speedup vs baseline: 1.4704x; 1.4704x over previous
//
#include <hip/hip_runtime.h>
#include <hip/hip_bf16.h>

typedef __hip_bfloat16 bf16;
using short8  = __attribute__((ext_vector_type(8))) short;
using floatx4 = __attribute__((ext_vector_type(4))) float;

__device__ __forceinline__ float b2f(unsigned short u) {
    union { unsigned int i; float f; } v; v.i = ((unsigned int)u) << 16; return v.f;
}
__device__ __forceinline__ unsigned short f2b(float f) {
    bf16 h = __float2bfloat16(f);
    return *(unsigned short*)&h;
}

// ---------------------------------------------------------------------------
// Workspace layout (bytes) — NON-OVERLAPPING:
//   dynk  @ 0        : fp32 (k1 6144 | k2T 131072 | k3T 147456 | k4T 524288 | k5T 262144 els)
//   stats @ 4284416  : 30720 fp32, 16 replicas per layer -> ends 4407296
//   WT    @ 4407296  : bf16 -> ends 5275648
//   S1    @ 5308416  : bf16 y1/y2/y3/y4 -> ends 72417280
//   S2    @ 72417280 : bf16 A2/A3/A4/A5 -> ends 89194496
//   aff   @ 89194496 : 1920 fp32 BN affine
//
// HARD-WON RULES (r7-r15, all measured):
//  - Never cap min-waves below the scheduler's live set -> TCC spills.
//  - Never put __threadfence in a wide kernel's epilogue: 4096 per-block
//    L2 writeback/invalidates cut effective HBM BW 4x (r15: l1 44->180 µs).
//    The 1-block bn_prep launch (~2 µs) is the cheaper pattern.
//  - dw prologue hoisted: dynk pre-transposed in prep, BN affine in bn_prep.
// ---------------------------------------------------------------------------
#define NREP 16

__global__ __launch_bounds__(256) void prep_kernel(
    const int* __restrict__ label, const float* __restrict__ emb,
    const float* __restrict__ l1w, const float* __restrict__ l1b,
    const float* __restrict__ l2w, const float* __restrict__ l2b,
    const float* __restrict__ l3w, const float* __restrict__ l3b,
    const float* __restrict__ l4w, const float* __restrict__ l4b,
    const float* __restrict__ l5w, const float* __restrict__ l5b,
    float* __restrict__ dynk, float* __restrict__ stats,
    float* __restrict__ labelOut)
{
    const int tid = threadIdx.x;
    if (blockIdx.x == gridDim.x - 1) {                   // housekeeping block
        for (int i = tid; i < 30720; i += 256) stats[i] = 0.0f;
        if (tid < 128) labelOut[tid] = (float)label[tid];
        return;
    }
    int idx = blockIdx.x * 256 + tid;
    if (idx >= 1071104) return;
    const float* w; const float* bb; int loc, ckk, ksk, base;
    if (idx < 6144)        { w = l1w; bb = l1b; loc = idx;          ckk = 48;   ksk = 0;  base = 0;      }
    else if (idx < 137216) { w = l2w; bb = l2b; loc = idx - 6144;   ckk = 1024; ksk = 16; base = 6144;   }
    else if (idx < 284672) { w = l3w; bb = l3b; loc = idx - 137216; ckk = 1152; ksk = 9;  base = 137216; }
    else if (idx < 808960) { w = l4w; bb = l4b; loc = idx - 284672; ckk = 4096; ksk = 16; base = 284672; }
    else                   { w = l5w; bb = l5b; loc = idx - 808960; ckk = 2048; ksk = 4;  base = 808960; }
    int b   = loc / ckk;
    int col = loc - b * ckk;
    int lab = label[b];
    float acc = bb[col];
    #pragma unroll
    for (int m = 0; m < 5; ++m)
        acc = fmaf(emb[lab * 5 + m], w[m * ckk + col], acc);
    float val = tanhf(acc);
    if (ksk == 0) {
        dynk[idx] = val;                          // layer 1: [b][c*k*k]
    } else {
        int c  = col / ksk;                       // transposed: [b][tap][c]
        int t  = col - c * ksk;
        int Cl = ckk / ksk;
        dynk[base + b * ckk + t * Cl + c] = val;
    }
}

// per-layer BN affine from the 16 stats replicas (1 block, C threads)
__global__ void bn_prep(const float* __restrict__ st,
                        const float* __restrict__ gam, const float* __restrict__ bet,
                        float* __restrict__ aff, int C, float NINV)
{
    int c = threadIdx.x;
    if (c >= C) return;
    float s = 0.f, q = 0.f;
    #pragma unroll
    for (int r = 0; r < NREP; ++r) {
        s += st[r * 2 * C + c];
        q += st[r * 2 * C + C + c];
    }
    float m   = s * NINV;
    float var = fmaf(q, NINV, -m * m);
    float sc  = gam[c] * rsqrtf(var + 1e-5f);
    aff[c]     = sc;
    aff[C + c] = fmaf(-m, sc, bet[c]);
}

// transpose-convert channel-mix weights: WT[n][k] = bf16(W[k][n]), layers 2..5
__global__ __launch_bounds__(256) void wt_kernel(
    const float* __restrict__ w2, const float* __restrict__ w3,
    const float* __restrict__ w4, const float* __restrict__ w5,
    bf16* __restrict__ wt2, bf16* __restrict__ wt3,
    bf16* __restrict__ wt4, bf16* __restrict__ wt5)
{
    __shared__ float T[32][33];
    const int tid = threadIdx.x;
    int t = blockIdx.x;
    const float* W; bf16* WT; int K, N, tl;
    if (t < 8)        { W = w2; WT = wt2; K = 64;  N = 128; tl = t; }
    else if (t < 40)  { W = w3; WT = wt3; K = 128; N = 256; tl = t - 8; }
    else if (t < 168) { W = w4; WT = wt4; K = 256; N = 512; tl = t - 40; }
    else              { W = w5; WT = wt5; K = 512; N = 512; tl = t - 168; }
    const int NT = N >> 5;
    const int kt = tl / NT, nt = tl - kt * NT;
    const int k0 = kt * 32, n0 = nt * 32;
    const int cc = tid & 31, rr = tid >> 5;
    #pragma unroll
    for (int it = 0; it < 4; ++it) {
        int k = rr + it * 8;
        T[k][cc] = W[(long)(k0 + k) * N + n0 + cc];
    }
    __syncthreads();
    #pragma unroll
    for (int it = 0; it < 4; ++it) {
        int n = rr + it * 8;
        WT[(long)(n0 + n) * K + k0 + cc] = __float2bfloat16(T[cc][n]);
    }
}

// ---------------------------------------------------------------------------
// Layer 1: 16w x 8h tile per block, 128 threads, 4096 blocks, ~11 KB LDS.
// Staging: fixed 15-slot fully-unrolled predicated loop (batched loads).
// NO device-scope fence in the epilogue (r15 lesson).
// ---------------------------------------------------------------------------
__global__ __launch_bounds__(128) void fused_l1_v5(
    const float* __restrict__ xf, const float* __restrict__ dynk,
    const float* __restrict__ W, const float* __restrict__ bias,
    bf16* __restrict__ y, float* __restrict__ statsOut)
{
    constexpr int HIN = 128, HOUT = 64;
    constexpr int TW = 16, TH = 8;
    constexpr int PS  = 36;
    constexpr int PCH = 18 * PS;

    __shared__ float patch[3 * PCH];
    __shared__ __align__(16) float dwT[16 * 28];
    __shared__ float Wlds[192];
    __shared__ float klds[48];
    __shared__ float biasL[64];
    __shared__ float sums[64], sqs[64];

    const int tid = threadIdx.x;
    const int b   = blockIdx.x >> 5;
    const int tl  = blockIdx.x & 31;
    const int ty0 = (tl >> 2) * TH;
    const int tx0 = (tl & 3) * TW;

    if (tid < 48) klds[tid] = dynk[b * 48 + tid];
    for (int i = tid; i < 192; i += 128) Wlds[i] = W[i];
    if (tid < 64) { biasL[tid] = bias[tid]; sums[tid] = 0.f; sqs[tid] = 0.f; }

    {   // stage padded patch: 1836 floats, 15 fixed slots/thread, batched loads
        const int iy0 = ty0 * 2 - 1, ix0 = tx0 * 2 - 1;
        #pragma unroll
        for (int k = 0; k < 15; ++k) {
            int i  = tid + k * 128;
            int c  = i / 612;
            int r  = i - c * 612;
            int py = r / 34, px = r - py * 34;
            int gy = iy0 + py, gx = ix0 + px;
            bool slot = (i < 1836);
            bool inb  = slot && ((unsigned)gy < (unsigned)HIN) && ((unsigned)gx < (unsigned)HIN);
            float v = 0.f;
            if (inb) v = xf[((long)b * 3 + c) * (HIN * HIN) + gy * HIN + gx];
            if (slot) patch[c * PCH + py * PS + px] = v;
        }
    }
    __syncthreads();

    {   // depthwise conv: thread = pixel
        const int py = tid >> 4, px = tid & 15;
        const int pixg = tid >> 3, j = tid & 7;
        #pragma unroll
        for (int c = 0; c < 3; ++c) {
            const float* pb = &patch[c * PCH + (py * 2) * PS + px * 2];
            float a = 0.f;
            #pragma unroll
            for (int kh = 0; kh < 4; ++kh)
                #pragma unroll
                for (int kw = 0; kw < 4; ++kw)
                    a = fmaf(pb[kh * PS + kw], klds[c * 16 + kh * 4 + kw], a);
            dwT[pixg * 28 + j * 3 + c] = a;
        }
    }
    __syncthreads();

    {   // mix + lrelu + stats + coalesced store
        const int cq = tid & 7, pixg = tid >> 3;
        const int d0 = cq * 8;
        float Wr[3][8], bi[8];
        #pragma unroll
        for (int c = 0; c < 3; ++c)
            #pragma unroll
            for (int t = 0; t < 8; ++t) Wr[c][t] = Wlds[c * 64 + d0 + t];
        #pragma unroll
        for (int t = 0; t < 8; ++t) bi[t] = biasL[d0 + t];

        float dv[24];
        #pragma unroll
        for (int q4 = 0; q4 < 6; ++q4)
            *(float4*)&dv[q4 * 4] = *(const float4*)&dwT[pixg * 28 + q4 * 4];

        float sreg[8] = {}, qreg[8] = {};
        #pragma unroll
        for (int j = 0; j < 8; ++j) {
            const int pos = pixg * 8 + j;
            const float dv0 = dv[j * 3 + 0];
            const float dv1 = dv[j * 3 + 1];
            const float dv2 = dv[j * 3 + 2];
            const int py = pos >> 4, px = pos & 15;
            const long row = ((long)(b * HOUT + ty0 + py)) * HOUT + tx0 + px;
            union { uint4 v; unsigned short us[8]; } pk;
            #pragma unroll
            for (int t = 0; t < 8; ++t) {
                float v = fmaf(dv0, Wr[0][t], fmaf(dv1, Wr[1][t], fmaf(dv2, Wr[2][t], bi[t])));
                v = v > 0.f ? v : 0.2f * v;
                sreg[t] += v;
                qreg[t] = fmaf(v, v, qreg[t]);
                pk.us[t] = f2b(v);
            }
            *(uint4*)&y[row * 64 + d0] = pk.v;
        }
        #pragma unroll
        for (int m = 8; m < 64; m <<= 1)
            #pragma unroll
            for (int t = 0; t < 8; ++t) {
                sreg[t] += __shfl_xor(sreg[t], m);
                qreg[t] += __shfl_xor(qreg[t], m);
            }
        if ((tid & 63) < 8) {
            #pragma unroll
            for (int t = 0; t < 8; ++t) {
                atomicAdd(&sums[d0 + t], sreg[t]);
                atomicAdd(&sqs [d0 + t], qreg[t]);
            }
        }
    }
    __syncthreads();
    {
        const int rep = blockIdx.x & (NREP - 1);
        if (tid < 64) {
            atomicAdd(&statsOut[rep * 128 + tid],      sums[tid]);
            atomicAdd(&statsOut[rep * 128 + 64 + tid], sqs[tid]);
        }
    }
}

// ---------------------------------------------------------------------------
// Direct-tap depthwise conv (layers 2..5): thread = (output pixel, 8 ch).
// ---------------------------------------------------------------------------
template<int C, int KS, int HIN, int HOUT, int STRIDE, int PAD, int NTHR>
__global__ __launch_bounds__(NTHR) void dw_direct(
    const bf16* __restrict__ x, const float* __restrict__ aff,
    const float* __restrict__ dynkT, bf16* __restrict__ outA)
{
    constexpr int G   = C / 8;
    constexpr int KSK = KS * KS;
    static_assert(NTHR == HOUT * G, "one output row per block");

    __shared__ __align__(16) float wlds[KSK * C];   // [tap][c], linear copy

    const int tid = threadIdx.x;
    const int b   = blockIdx.x / HOUT;
    const int oy  = blockIdx.x % HOUT;

    {
        const float* src = dynkT + (long)b * (KSK * C);
        for (int i = tid * 4; i < KSK * C; i += NTHR * 4)
            *(float4*)&wlds[i] = *(const float4*)&src[i];
    }
    __syncthreads();

    const int g  = tid % G;
    const int ox = tid / G;
    const int c0 = g * 8;
    const int iy0 = oy * STRIDE - PAD;
    const int ix0 = ox * STRIDE - PAD;

    float sc[8], sh[8];
    {
        float4 a0 = *(const float4*)&aff[c0];
        float4 a1 = *(const float4*)&aff[c0 + 4];
        float4 b0 = *(const float4*)&aff[C + c0];
        float4 b1 = *(const float4*)&aff[C + c0 + 4];
        sc[0]=a0.x; sc[1]=a0.y; sc[2]=a0.z; sc[3]=a0.w;
        sc[4]=a1.x; sc[5]=a1.y; sc[6]=a1.z; sc[7]=a1.w;
        sh[0]=b0.x; sh[1]=b0.y; sh[2]=b0.z; sh[3]=b0.w;
        sh[4]=b1.x; sh[5]=b1.y; sh[6]=b1.z; sh[7]=b1.w;
    }

    float acc[8];
    #pragma unroll
    for (int ch = 0; ch < 8; ++ch) acc[ch] = 0.f;

    const bool interior = (iy0 >= 0) && (iy0 + KS <= HIN) &&
                          (ix0 >= 0) && (ix0 + KS <= HIN);

    if (interior) {
        const bf16* bp = x + ((long)(b * HIN + iy0) * HIN + ix0) * C + c0;
        uint4 v[KSK];
        #pragma unroll
        for (int kh = 0; kh < KS; ++kh)
            #pragma unroll
            for (int kw = 0; kw < KS; ++kw)
                v[kh * KS + kw] = *(const uint4*)(bp + (kh * HIN + kw) * C);
        #pragma unroll
        for (int t = 0; t < KSK; ++t) {
            const float* wp = &wlds[t * C + c0];
            float4 wa = *(const float4*)wp;
            float4 wb = *(const float4*)(wp + 4);
            const float wt[8] = {wa.x, wa.y, wa.z, wa.w, wb.x, wb.y, wb.z, wb.w};
            #pragma unroll
            for (int ch = 0; ch < 8; ++ch) {
                unsigned u = ((const unsigned*)&v[t])[ch >> 1];
                unsigned bits = (ch & 1) ? (u & 0xffff0000u) : (u << 16);
                float xb = fmaf(__uint_as_float(bits), sc[ch], sh[ch]);
                acc[ch] = fmaf(xb, wt[ch], acc[ch]);
            }
        }
    } else {
        #pragma unroll
        for (int kh = 0; kh < KS; ++kh) {
            const int iy = iy0 + kh;
            if ((unsigned)iy >= (unsigned)HIN) continue;
            #pragma unroll
            for (int kw = 0; kw < KS; ++kw) {
                const int ix = ix0 + kw;
                if ((unsigned)ix >= (unsigned)HIN) continue;
                uint4 v = *(const uint4*)&x[((long)(b * HIN + iy) * HIN + ix) * C + c0];
                const float* wp = &wlds[(kh * KS + kw) * C + c0];
                float4 wa = *(const float4*)wp;
                float4 wb = *(const float4*)(wp + 4);
                const float wt[8] = {wa.x, wa.y, wa.z, wa.w, wb.x, wb.y, wb.z, wb.w};
                #pragma unroll
                for (int ch = 0; ch < 8; ++ch) {
                    unsigned u = ((const unsigned*)&v)[ch >> 1];
                    unsigned bits = (ch & 1) ? (u & 0xffff0000u) : (u << 16);
                    float xb = fmaf(__uint_as_float(bits), sc[ch], sh[ch]);
                    acc[ch] = fmaf(xb, wt[ch], acc[ch]);
                }
            }
        }
    }

    union { uint4 v; unsigned short us[8]; } pk;
    #pragma unroll
    for (int ch = 0; ch < 8; ++ch) pk.us[ch] = f2b(acc[ch]);
    *(uint4*)&outA[((long)(b * HOUT + oy) * HOUT + ox) * C + c0] = pk.v;
}

// ---------------------------------------------------------------------------
// MFMA bf16 GEMM: C[M,COUT] = A[M,K] x W[K,COUT], 128x128 block tile, BK=64.
// ---------------------------------------------------------------------------
template<int K, int COUT, bool LAST>
__global__ __launch_bounds__(256) void gemm_layer(
    const bf16* __restrict__ A, const bf16* __restrict__ WT,
    const float* __restrict__ bias, bf16* __restrict__ y,
    float* __restrict__ statsOut, float* __restrict__ outF, int Mtiles)
{
    constexpr int SK = 72;
    constexpr int CS = 136;
    __shared__ __align__(16) unsigned short smem[18432];
    unsigned short* As  = smem;
    unsigned short* Bs  = smem + 9216;
    unsigned short* Csh = smem;
    __shared__ float sums[128], sqs[128];

    const int tid  = threadIdx.x;
    const int lane = tid & 63;
    const int w    = tid >> 6;
    const int wm   = (w >> 1) * 64, wn = (w & 1) * 64;
    const int lm   = lane & 15, lq = lane >> 4;
    const int mt   = blockIdx.x % Mtiles;
    const int nt   = blockIdx.x / Mtiles;
    const long m0  = (long)mt * 128;
    const int  n0  = nt * 128;

    floatx4 acc[4][4];
    #pragma unroll
    for (int i = 0; i < 4; ++i)
        #pragma unroll
        for (int j = 0; j < 4; ++j) acc[i][j] = (floatx4)0.0f;

    for (int kb = 0; kb < K; kb += 64) {
        __syncthreads();
        #pragma unroll
        for (int s = 0; s < 4; ++s) {
            int i = tid + s * 256;
            int m = i >> 3, q = i & 7;
            uint4 va = *(const uint4*)(A  + ((m0 + m) * K + kb + q * 8));
            uint4 vb = *(const uint4*)(WT + ((long)(n0 + m) * K + kb + q * 8));
            *(uint4*)&As[m * SK + q * 8] = va;
            *(uint4*)&Bs[m * SK + q * 8] = vb;
        }
        __syncthreads();
        #pragma unroll
        for (int h = 0; h < 2; ++h) {
            short8 af[4], bfr[4];
            #pragma unroll
            for (int i = 0; i < 4; ++i) {
                af[i]  = *(const short8*)&As[(wm + i * 16 + lm) * SK + h * 32 + lq * 8];
                bfr[i] = *(const short8*)&Bs[(wn + i * 16 + lm) * SK + h * 32 + lq * 8];
            }
            #pragma unroll
            for (int i = 0; i < 4; ++i)
                #pragma unroll
                for (int j = 0; j < 4; ++j)
                    acc[i][j] = __builtin_amdgcn_mfma_f32_16x16x32_bf16(af[i], bfr[j], acc[i][j], 0, 0, 0);
        }
    }
    __syncthreads();

    float bj[4];
    #pragma unroll
    for (int j = 0; j < 4; ++j) bj[j] = bias[n0 + wn + j * 16 + lm];

    if constexpr (!LAST) {
        if (tid < 128) { sums[tid] = 0.f; sqs[tid] = 0.f; }
        #pragma unroll
        for (int i = 0; i < 4; ++i)
            #pragma unroll
            for (int j = 0; j < 4; ++j) {
                int c = wn + j * 16 + lm;
                #pragma unroll
                for (int rg = 0; rg < 4; ++rg) {
                    int r = wm + i * 16 + lq * 4 + rg;
                    float v = acc[i][j][rg] + bj[j];
                    v = v > 0.f ? v : 0.2f * v;
                    Csh[r * CS + c] = f2b(v);
                }
            }
        __syncthreads();
        const int cg = tid & 15, mr = tid >> 4;
        float sacc[8], qacc[8];
        #pragma unroll
        for (int t = 0; t < 8; ++t) { sacc[t] = 0.f; qacc[t] = 0.f; }
        #pragma unroll
        for (int it = 0; it < 8; ++it) {
            int m = mr + it * 16;
            uint4 pk = *(const uint4*)&Csh[m * CS + cg * 8];
            *(uint4*)&y[(m0 + m) * COUT + n0 + cg * 8] = pk;
            const unsigned short* pu = (const unsigned short*)&pk;
            #pragma unroll
            for (int t = 0; t < 8; ++t) {
                float f = b2f(pu[t]);
                sacc[t] += f;
                qacc[t] = fmaf(f, f, qacc[t]);
            }
        }
        #pragma unroll
        for (int t = 0; t < 8; ++t) {
            atomicAdd(&sums[cg * 8 + t], sacc[t]);
            atomicAdd(&sqs [cg * 8 + t], qacc[t]);
        }
        __syncthreads();
        {
            const int rep = blockIdx.x & (NREP - 1);
            if (tid < 128) {
                atomicAdd(&statsOut[rep * 2 * COUT + n0 + tid],        sums[tid]);
                atomicAdd(&statsOut[rep * 2 * COUT + COUT + n0 + tid], sqs[tid]);
            }
        }
    } else {
        #pragma unroll
        for (int i = 0; i < 4; ++i)
            #pragma unroll
            for (int j = 0; j < 4; ++j) {
                int c  = wn + j * 16 + lm;
                int rb = wm + i * 16 + lq * 4;
                ushort4 pk;
                unsigned short* pp = (unsigned short*)&pk;
                #pragma unroll
                for (int rg = 0; rg < 4; ++rg)
                    pp[rg] = f2b(acc[i][j][rg] + bj[j]);
                *(ushort4*)&Csh[c * CS + rb] = pk;
            }
        __syncthreads();
        const int mg = tid & 15, nr = tid >> 4;
        #pragma unroll
        for (int it = 0; it < 8; ++it) {
            int n = nr + it * 16;
            uint4 pk = *(const uint4*)&Csh[n * CS + mg * 8];
            const unsigned short* pu = (const unsigned short*)&pk;
            #pragma unroll
            for (int t = 0; t < 8; ++t) {
                int m = (int)m0 + mg * 8 + t;
                int b = m / 49, pos = m - b * 49;
                float v = b2f(pu[t]);
                outF[((long)(b * 512 + n0 + n)) * 49 + pos] = 1.f / (1.f + __expf(-v));
            }
        }
    }
}

// ---------------------------------------------------------------------------

extern "C" void kernel_launch(void* const* d_in, const int* in_sizes, int n_in,
                              void* d_out, int out_size, void* d_ws, size_t ws_size,
                              hipStream_t stream)
{
    const float* input = (const float*)d_in[0];
    const int*   label = (const int*)d_in[1];
    const float* emb   = (const float*)d_in[2];
    const float* lw[5] = {(const float*)d_in[3], (const float*)d_in[5], (const float*)d_in[7],
                          (const float*)d_in[9], (const float*)d_in[11]};
    const float* lb[5] = {(const float*)d_in[4], (const float*)d_in[6], (const float*)d_in[8],
                          (const float*)d_in[10], (const float*)d_in[12]};
    const float* cmw[5] = {(const float*)d_in[13], (const float*)d_in[15], (const float*)d_in[17],
                           (const float*)d_in[19], (const float*)d_in[21]};
    const float* cmb[5] = {(const float*)d_in[14], (const float*)d_in[16], (const float*)d_in[18],
                           (const float*)d_in[20], (const float*)d_in[22]};
    const float* bng[4] = {(const float*)d_in[23], (const float*)d_in[25],
                           (const float*)d_in[27], (const float*)d_in[29]};
    const float* bnb[4] = {(const float*)d_in[24], (const float*)d_in[26],
                           (const float*)d_in[28], (const float*)d_in[30]};
    float* out = (float*)d_out;

    float* wsf   = (float*)d_ws;
    float* dynk  = wsf;
    float* stats = wsf + 1071104;
    const float* k1  = dynk;
    const float* k2T = dynk + 6144;
    const float* k3T = dynk + 137216;
    const float* k4T = dynk + 284672;
    const float* k5T = dynk + 808960;
    float* st1 = stats;
    float* st2 = stats + 2048;
    float* st3 = stats + 6144;
    float* st4 = stats + 14336;

    bf16* wt  = (bf16*)((char*)d_ws + 4407296);
    bf16* wt2 = wt;
    bf16* wt3 = wt + 8192;
    bf16* wt4 = wt + 40960;
    bf16* wt5 = wt + 172032;
    bf16* S1  = (bf16*)((char*)d_ws + 5308416);
    bf16* S2  = (bf16*)((char*)d_ws + 72417280);
    float* affBase = (float*)((char*)d_ws + 89194496);
    float* aff1 = affBase;          // 128
    float* aff2 = affBase + 128;    // 256
    float* aff3 = affBase + 384;    // 512
    float* aff4 = affBase + 896;    // 1024

    prep_kernel<<<4186, 256, 0, stream>>>(label, emb,
        lw[0], lb[0], lw[1], lb[1], lw[2], lb[2], lw[3], lb[3], lw[4], lb[4],
        dynk, stats, out + 3211264);
    wt_kernel<<<424, 256, 0, stream>>>(cmw[1], cmw[2], cmw[3], cmw[4],
                                       wt2, wt3, wt4, wt5);

    // L1: fused (K=3) -> y1 + st1
    fused_l1_v5<<<4096, 128, 0, stream>>>(input, k1, cmw[0], cmb[0], S1, st1);

    // L2
    bn_prep<<<1, 64, 0, stream>>>(st1, bng[0], bnb[0], aff1, 64, 1.f / 524288.f);
    dw_direct<64, 4, 64, 32, 2, 1, 256><<<4096, 256, 0, stream>>>(S1, aff1, k2T, S2);
    gemm_layer<64, 128, false><<<1024, 256, 0, stream>>>(
        S2, wt2, cmb[1], S1, st2, nullptr, 1024);

    // L3
    bn_prep<<<1, 128, 0, stream>>>(st2, bng[1], bnb[1], aff2, 128, 1.f / 131072.f);
    dw_direct<128, 3, 32, 16, 2, 1, 256><<<2048, 256, 0, stream>>>(S1, aff2, k3T, S2);
    gemm_layer<128, 256, false><<<512, 256, 0, stream>>>(
        S2, wt3, cmb[2], S1, st3, nullptr, 256);

    // L4
    bn_prep<<<1, 256, 0, stream>>>(st3, bng[2], bnb[2], aff3, 256, 1.f / 32768.f);
    dw_direct<256, 4, 16, 8, 2, 1, 256><<<1024, 256, 0, stream>>>(S1, aff3, k4T, S2);
    gemm_layer<256, 512, false><<<256, 256, 0, stream>>>(
        S2, wt4, cmb[3], S1, st4, nullptr, 64);

    // L5
    bn_prep<<<1, 512, 0, stream>>>(st4, bng[3], bnb[3], aff4, 512, 1.f / 8192.f);
    dw_direct<512, 2, 8, 7, 1, 0, 448><<<896, 448, 0, stream>>>(S1, aff4, k5T, S2);
    gemm_layer<512, 512, true><<<196, 256, 0, stream>>>(
        S2, wt5, cmb[4], nullptr, nullptr, out, 49);
}

// Round 17
// 327.097 us; speedup vs baseline: 1.4724x; 1.0013x over previous
//
#include <hip/hip_runtime.h>
#include <hip/hip_bf16.h>

typedef __hip_bfloat16 bf16;
using short8  = __attribute__((ext_vector_type(8))) short;
using floatx4 = __attribute__((ext_vector_type(4))) float;

__device__ __forceinline__ float b2f(unsigned short u) {
    union { unsigned int i; float f; } v; v.i = ((unsigned int)u) << 16; return v.f;
}
__device__ __forceinline__ unsigned short f2b(float f) {
    bf16 h = __float2bfloat16(f);
    return *(unsigned short*)&h;
}

// ---------------------------------------------------------------------------
// Workspace layout (bytes) — NON-OVERLAPPING:
//   dynk  @ 0        : fp32 (k1 6144 | k2T 131072 | k3T 147456 | k4T 524288 | k5T 262144 els)
//   stats @ 4284416  : 30720 fp32, 16 replicas per layer -> ends 4407296
//   WT    @ 4407296  : bf16 -> ends 5275648
//   S1    @ 5308416  : bf16 y1/y2/y3/y4 -> ends 72417280
//   S2    @ 72417280 : bf16 A2/A3/A4/A5 -> ends 89194496
//   aff   @ 89194496 : 1920 fp32 BN affine
//
// HARD-WON RULES (r7-r15, all measured):
//  - Never cap min-waves below the scheduler's live set -> TCC spills.
//  - Never put __threadfence in a wide kernel's epilogue (r15: 4x BW loss).
//  - dw prologue hoisted: dynk pre-transposed in prep, BN affine in bn_prep.
//  - l1 geometry (r16): 256-thr/20KB blocks -> 32 waves/CU, 2048 blocks =
//    exactly 8/CU = one residency round (128-thr version: 26 waves + drain).
// ---------------------------------------------------------------------------
#define NREP 16

__global__ __launch_bounds__(256) void prep_kernel(
    const int* __restrict__ label, const float* __restrict__ emb,
    const float* __restrict__ l1w, const float* __restrict__ l1b,
    const float* __restrict__ l2w, const float* __restrict__ l2b,
    const float* __restrict__ l3w, const float* __restrict__ l3b,
    const float* __restrict__ l4w, const float* __restrict__ l4b,
    const float* __restrict__ l5w, const float* __restrict__ l5b,
    float* __restrict__ dynk, float* __restrict__ stats,
    float* __restrict__ labelOut)
{
    const int tid = threadIdx.x;
    if (blockIdx.x == gridDim.x - 1) {                   // housekeeping block
        for (int i = tid; i < 30720; i += 256) stats[i] = 0.0f;
        if (tid < 128) labelOut[tid] = (float)label[tid];
        return;
    }
    int idx = blockIdx.x * 256 + tid;
    if (idx >= 1071104) return;
    const float* w; const float* bb; int loc, ckk, ksk, base;
    if (idx < 6144)        { w = l1w; bb = l1b; loc = idx;          ckk = 48;   ksk = 0;  base = 0;      }
    else if (idx < 137216) { w = l2w; bb = l2b; loc = idx - 6144;   ckk = 1024; ksk = 16; base = 6144;   }
    else if (idx < 284672) { w = l3w; bb = l3b; loc = idx - 137216; ckk = 1152; ksk = 9;  base = 137216; }
    else if (idx < 808960) { w = l4w; bb = l4b; loc = idx - 284672; ckk = 4096; ksk = 16; base = 284672; }
    else                   { w = l5w; bb = l5b; loc = idx - 808960; ckk = 2048; ksk = 4;  base = 808960; }
    int b   = loc / ckk;
    int col = loc - b * ckk;
    int lab = label[b];
    float acc = bb[col];
    #pragma unroll
    for (int m = 0; m < 5; ++m)
        acc = fmaf(emb[lab * 5 + m], w[m * ckk + col], acc);
    float val = tanhf(acc);
    if (ksk == 0) {
        dynk[idx] = val;                          // layer 1: [b][c*k*k]
    } else {
        int c  = col / ksk;                       // transposed: [b][tap][c]
        int t  = col - c * ksk;
        int Cl = ckk / ksk;
        dynk[base + b * ckk + t * Cl + c] = val;
    }
}

// per-layer BN affine from the 16 stats replicas (1 block, C threads)
__global__ void bn_prep(const float* __restrict__ st,
                        const float* __restrict__ gam, const float* __restrict__ bet,
                        float* __restrict__ aff, int C, float NINV)
{
    int c = threadIdx.x;
    if (c >= C) return;
    float s = 0.f, q = 0.f;
    #pragma unroll
    for (int r = 0; r < NREP; ++r) {
        s += st[r * 2 * C + c];
        q += st[r * 2 * C + C + c];
    }
    float m   = s * NINV;
    float var = fmaf(q, NINV, -m * m);
    float sc  = gam[c] * rsqrtf(var + 1e-5f);
    aff[c]     = sc;
    aff[C + c] = fmaf(-m, sc, bet[c]);
}

// transpose-convert channel-mix weights: WT[n][k] = bf16(W[k][n]), layers 2..5
__global__ __launch_bounds__(256) void wt_kernel(
    const float* __restrict__ w2, const float* __restrict__ w3,
    const float* __restrict__ w4, const float* __restrict__ w5,
    bf16* __restrict__ wt2, bf16* __restrict__ wt3,
    bf16* __restrict__ wt4, bf16* __restrict__ wt5)
{
    __shared__ float T[32][33];
    const int tid = threadIdx.x;
    int t = blockIdx.x;
    const float* W; bf16* WT; int K, N, tl;
    if (t < 8)        { W = w2; WT = wt2; K = 64;  N = 128; tl = t; }
    else if (t < 40)  { W = w3; WT = wt3; K = 128; N = 256; tl = t - 8; }
    else if (t < 168) { W = w4; WT = wt4; K = 256; N = 512; tl = t - 40; }
    else              { W = w5; WT = wt5; K = 512; N = 512; tl = t - 168; }
    const int NT = N >> 5;
    const int kt = tl / NT, nt = tl - kt * NT;
    const int k0 = kt * 32, n0 = nt * 32;
    const int cc = tid & 31, rr = tid >> 5;
    #pragma unroll
    for (int it = 0; it < 4; ++it) {
        int k = rr + it * 8;
        T[k][cc] = W[(long)(k0 + k) * N + n0 + cc];
    }
    __syncthreads();
    #pragma unroll
    for (int it = 0; it < 4; ++it) {
        int n = rr + it * 8;
        WT[(long)(n0 + n) * K + k0 + cc] = __float2bfloat16(T[cc][n]);
    }
}

// ---------------------------------------------------------------------------
// Layer 1 v6: 32w x 8h tile per block, 256 threads, 2048 blocks, ~20 KB LDS
// -> 8 blocks/CU x 4 waves = 32 waves/CU, exactly one residency round.
// ---------------------------------------------------------------------------
__global__ __launch_bounds__(256) void fused_l1_v6(
    const float* __restrict__ xf, const float* __restrict__ dynk,
    const float* __restrict__ W, const float* __restrict__ bias,
    bf16* __restrict__ y, float* __restrict__ statsOut)
{
    constexpr int HIN = 128, HOUT = 64;
    constexpr int TW = 32, TH = 8;
    constexpr int PS  = 68;                 // patch row stride (floats), 272B rows
    constexpr int PCH = 18 * PS;            // 1224 floats per channel

    __shared__ float patch[3 * PCH];        // 14688 B
    __shared__ __align__(16) float dwT[32 * 28];   // [pixg][j*3+c]
    __shared__ float Wlds[192];
    __shared__ float klds[48];
    __shared__ float biasL[64];
    __shared__ float sums[64], sqs[64];

    const int tid = threadIdx.x;
    const int b   = blockIdx.x >> 4;        // 16 tiles per sample
    const int tl  = blockIdx.x & 15;
    const int ty0 = (tl >> 1) * TH;
    const int tx0 = (tl & 1) * TW;

    if (tid < 48) klds[tid] = dynk[b * 48 + tid];
    if (tid >= 64 && tid < 256) Wlds[tid - 64] = W[tid - 64];
    if (tid < 64) { biasL[tid] = bias[tid]; sums[tid] = 0.f; sqs[tid] = 0.f; }

    {   // stage padded patch: 3x18x68 slots (cols 66,67 zero), 15 fixed slots
        const int iy0 = ty0 * 2 - 1, ix0 = tx0 * 2 - 1;
        #pragma unroll
        for (int k = 0; k < 15; ++k) {
            int i  = tid + k * 256;
            int c  = i / 1224;
            int r  = i - c * 1224;
            int py = r / 68, px = r - py * 68;
            int gy = iy0 + py, gx = ix0 + px;
            bool slot = (i < 3672);
            bool inb  = slot && (px < 66) &&
                        ((unsigned)gy < (unsigned)HIN) && ((unsigned)gx < (unsigned)HIN);
            float v = 0.f;
            if (inb) v = xf[((long)b * 3 + c) * (HIN * HIN) + gy * HIN + gx];
            if (slot) patch[c * PCH + py * PS + px] = v;
        }
    }
    __syncthreads();

    {   // depthwise conv: thread = pixel (256 pixels)
        const int py = tid >> 5, px = tid & 31;
        const int pixg = tid >> 3, j = tid & 7;
        #pragma unroll
        for (int c = 0; c < 3; ++c) {
            const float* pb = &patch[c * PCH + (py * 2) * PS + px * 2];
            float a = 0.f;
            #pragma unroll
            for (int kh = 0; kh < 4; ++kh)
                #pragma unroll
                for (int kw = 0; kw < 4; ++kw)
                    a = fmaf(pb[kh * PS + kw], klds[c * 16 + kh * 4 + kw], a);
            dwT[pixg * 28 + j * 3 + c] = a;
        }
    }
    __syncthreads();

    {   // mix + lrelu + stats + coalesced store: thread = (cq 0..7, pixg 0..31)
        const int cq = tid & 7, pixg = tid >> 3;
        const int d0 = cq * 8;
        float Wr[3][8], bi[8];
        #pragma unroll
        for (int c = 0; c < 3; ++c)
            #pragma unroll
            for (int t = 0; t < 8; ++t) Wr[c][t] = Wlds[c * 64 + d0 + t];
        #pragma unroll
        for (int t = 0; t < 8; ++t) bi[t] = biasL[d0 + t];

        float dv[24];
        #pragma unroll
        for (int q4 = 0; q4 < 6; ++q4)
            *(float4*)&dv[q4 * 4] = *(const float4*)&dwT[pixg * 28 + q4 * 4];

        float sreg[8] = {}, qreg[8] = {};
        #pragma unroll
        for (int j = 0; j < 8; ++j) {
            const int pos = pixg * 8 + j;       // 0..255
            const float dv0 = dv[j * 3 + 0];
            const float dv1 = dv[j * 3 + 1];
            const float dv2 = dv[j * 3 + 2];
            const int py = pos >> 5, px = pos & 31;
            const long row = ((long)(b * HOUT + ty0 + py)) * HOUT + tx0 + px;
            union { uint4 v; unsigned short us[8]; } pk;
            #pragma unroll
            for (int t = 0; t < 8; ++t) {
                float v = fmaf(dv0, Wr[0][t], fmaf(dv1, Wr[1][t], fmaf(dv2, Wr[2][t], bi[t])));
                v = v > 0.f ? v : 0.2f * v;
                sreg[t] += v;
                qreg[t] = fmaf(v, v, qreg[t]);
                pk.us[t] = f2b(v);
            }
            *(uint4*)&y[row * 64 + d0] = pk.v;
        }
        // reduce over pixg within wave (lane bits 3..5), then LDS-combine waves
        #pragma unroll
        for (int m = 8; m < 64; m <<= 1)
            #pragma unroll
            for (int t = 0; t < 8; ++t) {
                sreg[t] += __shfl_xor(sreg[t], m);
                qreg[t] += __shfl_xor(qreg[t], m);
            }
        if ((tid & 63) < 8) {
            #pragma unroll
            for (int t = 0; t < 8; ++t) {
                atomicAdd(&sums[d0 + t], sreg[t]);
                atomicAdd(&sqs [d0 + t], qreg[t]);
            }
        }
    }
    __syncthreads();
    {
        const int rep = blockIdx.x & (NREP - 1);
        if (tid < 64) {
            atomicAdd(&statsOut[rep * 128 + tid],      sums[tid]);
            atomicAdd(&statsOut[rep * 128 + 64 + tid], sqs[tid]);
        }
    }
}

// ---------------------------------------------------------------------------
// Direct-tap depthwise conv (layers 2..5): thread = (output pixel, 8 ch).
// ---------------------------------------------------------------------------
template<int C, int KS, int HIN, int HOUT, int STRIDE, int PAD, int NTHR>
__global__ __launch_bounds__(NTHR) void dw_direct(
    const bf16* __restrict__ x, const float* __restrict__ aff,
    const float* __restrict__ dynkT, bf16* __restrict__ outA)
{
    constexpr int G   = C / 8;
    constexpr int KSK = KS * KS;
    static_assert(NTHR == HOUT * G, "one output row per block");

    __shared__ __align__(16) float wlds[KSK * C];   // [tap][c], linear copy

    const int tid = threadIdx.x;
    const int b   = blockIdx.x / HOUT;
    const int oy  = blockIdx.x % HOUT;

    {
        const float* src = dynkT + (long)b * (KSK * C);
        for (int i = tid * 4; i < KSK * C; i += NTHR * 4)
            *(float4*)&wlds[i] = *(const float4*)&src[i];
    }
    __syncthreads();

    const int g  = tid % G;
    const int ox = tid / G;
    const int c0 = g * 8;
    const int iy0 = oy * STRIDE - PAD;
    const int ix0 = ox * STRIDE - PAD;

    float sc[8], sh[8];
    {
        float4 a0 = *(const float4*)&aff[c0];
        float4 a1 = *(const float4*)&aff[c0 + 4];
        float4 b0 = *(const float4*)&aff[C + c0];
        float4 b1 = *(const float4*)&aff[C + c0 + 4];
        sc[0]=a0.x; sc[1]=a0.y; sc[2]=a0.z; sc[3]=a0.w;
        sc[4]=a1.x; sc[5]=a1.y; sc[6]=a1.z; sc[7]=a1.w;
        sh[0]=b0.x; sh[1]=b0.y; sh[2]=b0.z; sh[3]=b0.w;
        sh[4]=b1.x; sh[5]=b1.y; sh[6]=b1.z; sh[7]=b1.w;
    }

    float acc[8];
    #pragma unroll
    for (int ch = 0; ch < 8; ++ch) acc[ch] = 0.f;

    const bool interior = (iy0 >= 0) && (iy0 + KS <= HIN) &&
                          (ix0 >= 0) && (ix0 + KS <= HIN);

    if (interior) {
        const bf16* bp = x + ((long)(b * HIN + iy0) * HIN + ix0) * C + c0;
        uint4 v[KSK];
        #pragma unroll
        for (int kh = 0; kh < KS; ++kh)
            #pragma unroll
            for (int kw = 0; kw < KS; ++kw)
                v[kh * KS + kw] = *(const uint4*)(bp + (kh * HIN + kw) * C);
        #pragma unroll
        for (int t = 0; t < KSK; ++t) {
            const float* wp = &wlds[t * C + c0];
            float4 wa = *(const float4*)wp;
            float4 wb = *(const float4*)(wp + 4);
            const float wt[8] = {wa.x, wa.y, wa.z, wa.w, wb.x, wb.y, wb.z, wb.w};
            #pragma unroll
            for (int ch = 0; ch < 8; ++ch) {
                unsigned u = ((const unsigned*)&v[t])[ch >> 1];
                unsigned bits = (ch & 1) ? (u & 0xffff0000u) : (u << 16);
                float xb = fmaf(__uint_as_float(bits), sc[ch], sh[ch]);
                acc[ch] = fmaf(xb, wt[ch], acc[ch]);
            }
        }
    } else {
        #pragma unroll
        for (int kh = 0; kh < KS; ++kh) {
            const int iy = iy0 + kh;
            if ((unsigned)iy >= (unsigned)HIN) continue;
            #pragma unroll
            for (int kw = 0; kw < KS; ++kw) {
                const int ix = ix0 + kw;
                if ((unsigned)ix >= (unsigned)HIN) continue;
                uint4 v = *(const uint4*)&x[((long)(b * HIN + iy) * HIN + ix) * C + c0];
                const float* wp = &wlds[(kh * KS + kw) * C + c0];
                float4 wa = *(const float4*)wp;
                float4 wb = *(const float4*)(wp + 4);
                const float wt[8] = {wa.x, wa.y, wa.z, wa.w, wb.x, wb.y, wb.z, wb.w};
                #pragma unroll
                for (int ch = 0; ch < 8; ++ch) {
                    unsigned u = ((const unsigned*)&v)[ch >> 1];
                    unsigned bits = (ch & 1) ? (u & 0xffff0000u) : (u << 16);
                    float xb = fmaf(__uint_as_float(bits), sc[ch], sh[ch]);
                    acc[ch] = fmaf(xb, wt[ch], acc[ch]);
                }
            }
        }
    }

    union { uint4 v; unsigned short us[8]; } pk;
    #pragma unroll
    for (int ch = 0; ch < 8; ++ch) pk.us[ch] = f2b(acc[ch]);
    *(uint4*)&outA[((long)(b * HOUT + oy) * HOUT + ox) * C + c0] = pk.v;
}

// ---------------------------------------------------------------------------
// MFMA bf16 GEMM: C[M,COUT] = A[M,K] x W[K,COUT], 128x128 block tile, BK=64.
// ---------------------------------------------------------------------------
template<int K, int COUT, bool LAST>
__global__ __launch_bounds__(256) void gemm_layer(
    const bf16* __restrict__ A, const bf16* __restrict__ WT,
    const float* __restrict__ bias, bf16* __restrict__ y,
    float* __restrict__ statsOut, float* __restrict__ outF, int Mtiles)
{
    constexpr int SK = 72;
    constexpr int CS = 136;
    __shared__ __align__(16) unsigned short smem[18432];
    unsigned short* As  = smem;
    unsigned short* Bs  = smem + 9216;
    unsigned short* Csh = smem;
    __shared__ float sums[128], sqs[128];

    const int tid  = threadIdx.x;
    const int lane = tid & 63;
    const int w    = tid >> 6;
    const int wm   = (w >> 1) * 64, wn = (w & 1) * 64;
    const int lm   = lane & 15, lq = lane >> 4;
    const int mt   = blockIdx.x % Mtiles;
    const int nt   = blockIdx.x / Mtiles;
    const long m0  = (long)mt * 128;
    const int  n0  = nt * 128;

    floatx4 acc[4][4];
    #pragma unroll
    for (int i = 0; i < 4; ++i)
        #pragma unroll
        for (int j = 0; j < 4; ++j) acc[i][j] = (floatx4)0.0f;

    for (int kb = 0; kb < K; kb += 64) {
        __syncthreads();
        #pragma unroll
        for (int s = 0; s < 4; ++s) {
            int i = tid + s * 256;
            int m = i >> 3, q = i & 7;
            uint4 va = *(const uint4*)(A  + ((m0 + m) * K + kb + q * 8));
            uint4 vb = *(const uint4*)(WT + ((long)(n0 + m) * K + kb + q * 8));
            *(uint4*)&As[m * SK + q * 8] = va;
            *(uint4*)&Bs[m * SK + q * 8] = vb;
        }
        __syncthreads();
        #pragma unroll
        for (int h = 0; h < 2; ++h) {
            short8 af[4], bfr[4];
            #pragma unroll
            for (int i = 0; i < 4; ++i) {
                af[i]  = *(const short8*)&As[(wm + i * 16 + lm) * SK + h * 32 + lq * 8];
                bfr[i] = *(const short8*)&Bs[(wn + i * 16 + lm) * SK + h * 32 + lq * 8];
            }
            #pragma unroll
            for (int i = 0; i < 4; ++i)
                #pragma unroll
                for (int j = 0; j < 4; ++j)
                    acc[i][j] = __builtin_amdgcn_mfma_f32_16x16x32_bf16(af[i], bfr[j], acc[i][j], 0, 0, 0);
        }
    }
    __syncthreads();

    float bj[4];
    #pragma unroll
    for (int j = 0; j < 4; ++j) bj[j] = bias[n0 + wn + j * 16 + lm];

    if constexpr (!LAST) {
        if (tid < 128) { sums[tid] = 0.f; sqs[tid] = 0.f; }
        #pragma unroll
        for (int i = 0; i < 4; ++i)
            #pragma unroll
            for (int j = 0; j < 4; ++j) {
                int c = wn + j * 16 + lm;
                #pragma unroll
                for (int rg = 0; rg < 4; ++rg) {
                    int r = wm + i * 16 + lq * 4 + rg;
                    float v = acc[i][j][rg] + bj[j];
                    v = v > 0.f ? v : 0.2f * v;
                    Csh[r * CS + c] = f2b(v);
                }
            }
        __syncthreads();
        const int cg = tid & 15, mr = tid >> 4;
        float sacc[8], qacc[8];
        #pragma unroll
        for (int t = 0; t < 8; ++t) { sacc[t] = 0.f; qacc[t] = 0.f; }
        #pragma unroll
        for (int it = 0; it < 8; ++it) {
            int m = mr + it * 16;
            uint4 pk = *(const uint4*)&Csh[m * CS + cg * 8];
            *(uint4*)&y[(m0 + m) * COUT + n0 + cg * 8] = pk;
            const unsigned short* pu = (const unsigned short*)&pk;
            #pragma unroll
            for (int t = 0; t < 8; ++t) {
                float f = b2f(pu[t]);
                sacc[t] += f;
                qacc[t] = fmaf(f, f, qacc[t]);
            }
        }
        #pragma unroll
        for (int t = 0; t < 8; ++t) {
            atomicAdd(&sums[cg * 8 + t], sacc[t]);
            atomicAdd(&sqs [cg * 8 + t], qacc[t]);
        }
        __syncthreads();
        {
            const int rep = blockIdx.x & (NREP - 1);
            if (tid < 128) {
                atomicAdd(&statsOut[rep * 2 * COUT + n0 + tid],        sums[tid]);
                atomicAdd(&statsOut[rep * 2 * COUT + COUT + n0 + tid], sqs[tid]);
            }
        }
    } else {
        #pragma unroll
        for (int i = 0; i < 4; ++i)
            #pragma unroll
            for (int j = 0; j < 4; ++j) {
                int c  = wn + j * 16 + lm;
                int rb = wm + i * 16 + lq * 4;
                ushort4 pk;
                unsigned short* pp = (unsigned short*)&pk;
                #pragma unroll
                for (int rg = 0; rg < 4; ++rg)
                    pp[rg] = f2b(acc[i][j][rg] + bj[j]);
                *(ushort4*)&Csh[c * CS + rb] = pk;
            }
        __syncthreads();
        const int mg = tid & 15, nr = tid >> 4;
        #pragma unroll
        for (int it = 0; it < 8; ++it) {
            int n = nr + it * 16;
            uint4 pk = *(const uint4*)&Csh[n * CS + mg * 8];
            const unsigned short* pu = (const unsigned short*)&pk;
            #pragma unroll
            for (int t = 0; t < 8; ++t) {
                int m = (int)m0 + mg * 8 + t;
                int b = m / 49, pos = m - b * 49;
                float v = b2f(pu[t]);
                outF[((long)(b * 512 + n0 + n)) * 49 + pos] = 1.f / (1.f + __expf(-v));
            }
        }
    }
}

// ---------------------------------------------------------------------------

extern "C" void kernel_launch(void* const* d_in, const int* in_sizes, int n_in,
                              void* d_out, int out_size, void* d_ws, size_t ws_size,
                              hipStream_t stream)
{
    const float* input = (const float*)d_in[0];
    const int*   label = (const int*)d_in[1];
    const float* emb   = (const float*)d_in[2];
    const float* lw[5] = {(const float*)d_in[3], (const float*)d_in[5], (const float*)d_in[7],
                          (const float*)d_in[9], (const float*)d_in[11]};
    const float* lb[5] = {(const float*)d_in[4], (const float*)d_in[6], (const float*)d_in[8],
                          (const float*)d_in[10], (const float*)d_in[12]};
    const float* cmw[5] = {(const float*)d_in[13], (const float*)d_in[15], (const float*)d_in[17],
                           (const float*)d_in[19], (const float*)d_in[21]};
    const float* cmb[5] = {(const float*)d_in[14], (const float*)d_in[16], (const float*)d_in[18],
                           (const float*)d_in[20], (const float*)d_in[22]};
    const float* bng[4] = {(const float*)d_in[23], (const float*)d_in[25],
                           (const float*)d_in[27], (const float*)d_in[29]};
    const float* bnb[4] = {(const float*)d_in[24], (const float*)d_in[26],
                           (const float*)d_in[28], (const float*)d_in[30]};
    float* out = (float*)d_out;

    float* wsf   = (float*)d_ws;
    float* dynk  = wsf;
    float* stats = wsf + 1071104;
    const float* k1  = dynk;
    const float* k2T = dynk + 6144;
    const float* k3T = dynk + 137216;
    const float* k4T = dynk + 284672;
    const float* k5T = dynk + 808960;
    float* st1 = stats;
    float* st2 = stats + 2048;
    float* st3 = stats + 6144;
    float* st4 = stats + 14336;

    bf16* wt  = (bf16*)((char*)d_ws + 4407296);
    bf16* wt2 = wt;
    bf16* wt3 = wt + 8192;
    bf16* wt4 = wt + 40960;
    bf16* wt5 = wt + 172032;
    bf16* S1  = (bf16*)((char*)d_ws + 5308416);
    bf16* S2  = (bf16*)((char*)d_ws + 72417280);
    float* affBase = (float*)((char*)d_ws + 89194496);
    float* aff1 = affBase;          // 128
    float* aff2 = affBase + 128;    // 256
    float* aff3 = affBase + 384;    // 512
    float* aff4 = affBase + 896;    // 1024

    prep_kernel<<<4186, 256, 0, stream>>>(label, emb,
        lw[0], lb[0], lw[1], lb[1], lw[2], lb[2], lw[3], lb[3], lw[4], lb[4],
        dynk, stats, out + 3211264);
    wt_kernel<<<424, 256, 0, stream>>>(cmw[1], cmw[2], cmw[3], cmw[4],
                                       wt2, wt3, wt4, wt5);

    // L1: fused (K=3) -> y1 + st1
    fused_l1_v6<<<2048, 256, 0, stream>>>(input, k1, cmw[0], cmb[0], S1, st1);

    // L2
    bn_prep<<<1, 64, 0, stream>>>(st1, bng[0], bnb[0], aff1, 64, 1.f / 524288.f);
    dw_direct<64, 4, 64, 32, 2, 1, 256><<<4096, 256, 0, stream>>>(S1, aff1, k2T, S2);
    gemm_layer<64, 128, false><<<1024, 256, 0, stream>>>(
        S2, wt2, cmb[1], S1, st2, nullptr, 1024);

    // L3
    bn_prep<<<1, 128, 0, stream>>>(st2, bng[1], bnb[1], aff2, 128, 1.f / 131072.f);
    dw_direct<128, 3, 32, 16, 2, 1, 256><<<2048, 256, 0, stream>>>(S1, aff2, k3T, S2);
    gemm_layer<128, 256, false><<<512, 256, 0, stream>>>(
        S2, wt3, cmb[2], S1, st3, nullptr, 256);

    // L4
    bn_prep<<<1, 256, 0, stream>>>(st3, bng[2], bnb[2], aff3, 256, 1.f / 32768.f);
    dw_direct<256, 4, 16, 8, 2, 1, 256><<<1024, 256, 0, stream>>>(S1, aff3, k4T, S2);
    gemm_layer<256, 512, false><<<256, 256, 0, stream>>>(
        S2, wt4, cmb[3], S1, st4, nullptr, 64);

    // L5
    bn_prep<<<1, 512, 0, stream>>>(st4, bng[3], bnb[3], aff4, 512, 1.f / 8192.f);
    dw_direct<512, 2, 8, 7, 1, 0, 448><<<896, 448, 0, stream>>>(S1, aff4, k5T, S2);
    gemm_layer<512, 512, true><<<196, 256, 0, stream>>>(
        S2, wt5, cmb[4], nullptr, nullptr, out, 49);
}

// Round 21
// 324.869 us; speedup vs baseline: 1.4825x; 1.0069x over previous
//
#include <hip/hip_runtime.h>
#include <hip/hip_bf16.h>

typedef __hip_bfloat16 bf16;
using short8  = __attribute__((ext_vector_type(8))) short;
using floatx4 = __attribute__((ext_vector_type(4))) float;

__device__ __forceinline__ float b2f(unsigned short u) {
    union { unsigned int i; float f; } v; v.i = ((unsigned int)u) << 16; return v.f;
}
__device__ __forceinline__ unsigned short f2b(float f) {
    bf16 h = __float2bfloat16(f);
    return *(unsigned short*)&h;
}

// ---------------------------------------------------------------------------
// Workspace layout (bytes) -- NON-OVERLAPPING, sizes verified r20:
//   dynk  @ 0         : fp32 (k1 6144 | k2T 131072 | k3T 147456 | k4T 524288 | k5T 262144 els)
//   stats @ 4284416   : 30720 fp32, 16 replicas per layer -> ends 4407296
//   WT    @ 4407296   : bf16 -> ends 5275648
//   S1    @ 5308416   : bf16, 33554432 elems. y1 (33.5M) during L1/L2; then:
//       A3 @ +0 (4194304) | y3 @ +4194304 (8388608) | A4 @ +12582912 (2097152)
//       y4 @ +14680064 (4194304) | A5 @ +18874368 (3211264) -> ends 22085632
//   S2    @ 72417280  : bf16, y2 = 16777216 elems (33554432 B) -> ends 105971712
//   aff   @ 105971712 : 1920 fp32 BN affine -> ends 105979392 (~101 MB total)
//
// HARD-WON RULES (r6-r20, all measured):
//  - Workspace regions must be provably disjoint per kernel WITH SIZES
//    (r6 base overlap; r20 y2 sized for 64ch instead of 128ch -> NaN).
//  - Never cap min-waves below the scheduler's live set -> TCC spills.
//  - Never put __threadfence in a wide kernel's epilogue (r15: 4x BW loss).
//  - Short one-round kernels plateau at ~2-3x memory floor; remaining lever
//    is fusion (r17: dw2 folded into gemm2's A-staging, kills A2 round-trip).
// ---------------------------------------------------------------------------
#define NREP 16

__global__ __launch_bounds__(256) void prep_kernel(
    const int* __restrict__ label, const float* __restrict__ emb,
    const float* __restrict__ l1w, const float* __restrict__ l1b,
    const float* __restrict__ l2w, const float* __restrict__ l2b,
    const float* __restrict__ l3w, const float* __restrict__ l3b,
    const float* __restrict__ l4w, const float* __restrict__ l4b,
    const float* __restrict__ l5w, const float* __restrict__ l5b,
    float* __restrict__ dynk, float* __restrict__ stats,
    float* __restrict__ labelOut)
{
    const int tid = threadIdx.x;
    if (blockIdx.x == gridDim.x - 1) {                   // housekeeping block
        for (int i = tid; i < 30720; i += 256) stats[i] = 0.0f;
        if (tid < 128) labelOut[tid] = (float)label[tid];
        return;
    }
    int idx = blockIdx.x * 256 + tid;
    if (idx >= 1071104) return;
    const float* w; const float* bb; int loc, ckk, ksk, base;
    if (idx < 6144)        { w = l1w; bb = l1b; loc = idx;          ckk = 48;   ksk = 0;  base = 0;      }
    else if (idx < 137216) { w = l2w; bb = l2b; loc = idx - 6144;   ckk = 1024; ksk = 16; base = 6144;   }
    else if (idx < 284672) { w = l3w; bb = l3b; loc = idx - 137216; ckk = 1152; ksk = 9;  base = 137216; }
    else if (idx < 808960) { w = l4w; bb = l4b; loc = idx - 284672; ckk = 4096; ksk = 16; base = 284672; }
    else                   { w = l5w; bb = l5b; loc = idx - 808960; ckk = 2048; ksk = 4;  base = 808960; }
    int b   = loc / ckk;
    int col = loc - b * ckk;
    int lab = label[b];
    float acc = bb[col];
    #pragma unroll
    for (int m = 0; m < 5; ++m)
        acc = fmaf(emb[lab * 5 + m], w[m * ckk + col], acc);
    float val = tanhf(acc);
    if (ksk == 0) {
        dynk[idx] = val;                          // layer 1: [b][c*k*k]
    } else {
        int c  = col / ksk;                       // transposed: [b][tap][c]
        int t  = col - c * ksk;
        int Cl = ckk / ksk;
        dynk[base + b * ckk + t * Cl + c] = val;
    }
}

// per-layer BN affine from the 16 stats replicas (1 block, C threads)
__global__ void bn_prep(const float* __restrict__ st,
                        const float* __restrict__ gam, const float* __restrict__ bet,
                        float* __restrict__ aff, int C, float NINV)
{
    int c = threadIdx.x;
    if (c >= C) return;
    float s = 0.f, q = 0.f;
    #pragma unroll
    for (int r = 0; r < NREP; ++r) {
        s += st[r * 2 * C + c];
        q += st[r * 2 * C + C + c];
    }
    float m   = s * NINV;
    float var = fmaf(q, NINV, -m * m);
    float sc  = gam[c] * rsqrtf(var + 1e-5f);
    aff[c]     = sc;
    aff[C + c] = fmaf(-m, sc, bet[c]);
}

// transpose-convert channel-mix weights: WT[n][k] = bf16(W[k][n]), layers 2..5
__global__ __launch_bounds__(256) void wt_kernel(
    const float* __restrict__ w2, const float* __restrict__ w3,
    const float* __restrict__ w4, const float* __restrict__ w5,
    bf16* __restrict__ wt2, bf16* __restrict__ wt3,
    bf16* __restrict__ wt4, bf16* __restrict__ wt5)
{
    __shared__ float T[32][33];
    const int tid = threadIdx.x;
    int t = blockIdx.x;
    const float* W; bf16* WT; int K, N, tl;
    if (t < 8)        { W = w2; WT = wt2; K = 64;  N = 128; tl = t; }
    else if (t < 40)  { W = w3; WT = wt3; K = 128; N = 256; tl = t - 8; }
    else if (t < 168) { W = w4; WT = wt4; K = 256; N = 512; tl = t - 40; }
    else              { W = w5; WT = wt5; K = 512; N = 512; tl = t - 168; }
    const int NT = N >> 5;
    const int kt = tl / NT, nt = tl - kt * NT;
    const int k0 = kt * 32, n0 = nt * 32;
    const int cc = tid & 31, rr = tid >> 5;
    #pragma unroll
    for (int it = 0; it < 4; ++it) {
        int k = rr + it * 8;
        T[k][cc] = W[(long)(k0 + k) * N + n0 + cc];
    }
    __syncthreads();
    #pragma unroll
    for (int it = 0; it < 4; ++it) {
        int n = rr + it * 8;
        WT[(long)(n0 + n) * K + k0 + cc] = __float2bfloat16(T[cc][n]);
    }
}

// ---------------------------------------------------------------------------
// Layer 1 v6: 32w x 8h tile per block, 256 threads, 2048 blocks, ~20 KB LDS.
// ---------------------------------------------------------------------------
__global__ __launch_bounds__(256) void fused_l1_v6(
    const float* __restrict__ xf, const float* __restrict__ dynk,
    const float* __restrict__ W, const float* __restrict__ bias,
    bf16* __restrict__ y, float* __restrict__ statsOut)
{
    constexpr int HIN = 128, HOUT = 64;
    constexpr int TW = 32, TH = 8;
    constexpr int PS  = 68;
    constexpr int PCH = 18 * PS;

    __shared__ float patch[3 * PCH];
    __shared__ __align__(16) float dwT[32 * 28];
    __shared__ float Wlds[192];
    __shared__ float klds[48];
    __shared__ float biasL[64];
    __shared__ float sums[64], sqs[64];

    const int tid = threadIdx.x;
    const int b   = blockIdx.x >> 4;
    const int tl  = blockIdx.x & 15;
    const int ty0 = (tl >> 1) * TH;
    const int tx0 = (tl & 1) * TW;

    if (tid < 48) klds[tid] = dynk[b * 48 + tid];
    if (tid >= 64 && tid < 256) Wlds[tid - 64] = W[tid - 64];
    if (tid < 64) { biasL[tid] = bias[tid]; sums[tid] = 0.f; sqs[tid] = 0.f; }

    {
        const int iy0 = ty0 * 2 - 1, ix0 = tx0 * 2 - 1;
        #pragma unroll
        for (int k = 0; k < 15; ++k) {
            int i  = tid + k * 256;
            int c  = i / 1224;
            int r  = i - c * 1224;
            int py = r / 68, px = r - py * 68;
            int gy = iy0 + py, gx = ix0 + px;
            bool slot = (i < 3672);
            bool inb  = slot && (px < 66) &&
                        ((unsigned)gy < (unsigned)HIN) && ((unsigned)gx < (unsigned)HIN);
            float v = 0.f;
            if (inb) v = xf[((long)b * 3 + c) * (HIN * HIN) + gy * HIN + gx];
            if (slot) patch[c * PCH + py * PS + px] = v;
        }
    }
    __syncthreads();

    {
        const int py = tid >> 5, px = tid & 31;
        const int pixg = tid >> 3, j = tid & 7;
        #pragma unroll
        for (int c = 0; c < 3; ++c) {
            const float* pb = &patch[c * PCH + (py * 2) * PS + px * 2];
            float a = 0.f;
            #pragma unroll
            for (int kh = 0; kh < 4; ++kh)
                #pragma unroll
                for (int kw = 0; kw < 4; ++kw)
                    a = fmaf(pb[kh * PS + kw], klds[c * 16 + kh * 4 + kw], a);
            dwT[pixg * 28 + j * 3 + c] = a;
        }
    }
    __syncthreads();

    {
        const int cq = tid & 7, pixg = tid >> 3;
        const int d0 = cq * 8;
        float Wr[3][8], bi[8];
        #pragma unroll
        for (int c = 0; c < 3; ++c)
            #pragma unroll
            for (int t = 0; t < 8; ++t) Wr[c][t] = Wlds[c * 64 + d0 + t];
        #pragma unroll
        for (int t = 0; t < 8; ++t) bi[t] = biasL[d0 + t];

        float dv[24];
        #pragma unroll
        for (int q4 = 0; q4 < 6; ++q4)
            *(float4*)&dv[q4 * 4] = *(const float4*)&dwT[pixg * 28 + q4 * 4];

        float sreg[8] = {}, qreg[8] = {};
        #pragma unroll
        for (int j = 0; j < 8; ++j) {
            const int pos = pixg * 8 + j;
            const float dv0 = dv[j * 3 + 0];
            const float dv1 = dv[j * 3 + 1];
            const float dv2 = dv[j * 3 + 2];
            const int py = pos >> 5, px = pos & 31;
            const long row = ((long)(b * HOUT + ty0 + py)) * HOUT + tx0 + px;
            union { uint4 v; unsigned short us[8]; } pk;
            #pragma unroll
            for (int t = 0; t < 8; ++t) {
                float v = fmaf(dv0, Wr[0][t], fmaf(dv1, Wr[1][t], fmaf(dv2, Wr[2][t], bi[t])));
                v = v > 0.f ? v : 0.2f * v;
                sreg[t] += v;
                qreg[t] = fmaf(v, v, qreg[t]);
                pk.us[t] = f2b(v);
            }
            *(uint4*)&y[row * 64 + d0] = pk.v;
        }
        #pragma unroll
        for (int m = 8; m < 64; m <<= 1)
            #pragma unroll
            for (int t = 0; t < 8; ++t) {
                sreg[t] += __shfl_xor(sreg[t], m);
                qreg[t] += __shfl_xor(qreg[t], m);
            }
        if ((tid & 63) < 8) {
            #pragma unroll
            for (int t = 0; t < 8; ++t) {
                atomicAdd(&sums[d0 + t], sreg[t]);
                atomicAdd(&sqs [d0 + t], qreg[t]);
            }
        }
    }
    __syncthreads();
    {
        const int rep = blockIdx.x & (NREP - 1);
        if (tid < 64) {
            atomicAdd(&statsOut[rep * 128 + tid],      sums[tid]);
            atomicAdd(&statsOut[rep * 128 + 64 + tid], sqs[tid]);
        }
    }
}

// ---------------------------------------------------------------------------
// FUSED L2: dw (k4,s2,p1, 64->32) folded into gemm A-staging + MFMA + epilogue.
// Grid = 1024 blocks (M tiles of 128 rows), single 128-col n tile.
// y1 (S1) and y2 (S2, 16.8M elems) are disjoint.
// ---------------------------------------------------------------------------
__global__ __launch_bounds__(256) void gemm2_fused(
    const bf16* __restrict__ y1, const bf16* __restrict__ WT,
    const float* __restrict__ aff, const float* __restrict__ k2T,
    const float* __restrict__ bias, bf16* __restrict__ y,
    float* __restrict__ statsOut)
{
    constexpr int SK = 72;
    constexpr int CS = 136;
    __shared__ __align__(16) unsigned short smem[18432];
    unsigned short* As  = smem;
    unsigned short* Bs  = smem + 9216;
    unsigned short* Csh = smem;
    __shared__ float klds[1024];          // [tap][c] for this sample, 4 KB
    __shared__ float scL[64], shL[64];
    __shared__ float sums[128], sqs[128];

    const int tid  = threadIdx.x;
    const int lane = tid & 63;
    const int w    = tid >> 6;
    const int wm   = (w >> 1) * 64, wn = (w & 1) * 64;
    const int lm   = lane & 15, lq = lane >> 4;
    const long m0  = (long)blockIdx.x * 128;
    const int  b   = (int)(m0 >> 10);         // sample index (1024 px/sample)

    *(float4*)&klds[tid * 4] = *(const float4*)&k2T[b * 1024 + tid * 4];
    if (tid < 64) { scL[tid] = aff[tid]; shL[tid] = aff[64 + tid]; }
    #pragma unroll
    for (int s = 0; s < 4; ++s) {
        int i = tid + s * 256;                // 1024 granules of B (128 rows x 8)
        int n = i >> 3, q = i & 7;
        uint4 vb = *(const uint4*)(WT + (long)n * 64 + q * 8);
        *(uint4*)&Bs[n * SK + q * 8] = vb;
    }
    __syncthreads();

    // A staging with fused depthwise conv
    #pragma unroll
    for (int s = 0; s < 4; ++s) {
        int i = tid + s * 256;                // 1024 items: (m row, q chan-group)
        int m = i >> 3, q = i & 7;
        int pos = (int)((m0 + m) & 1023);
        int oy = pos >> 5, ox = pos & 31;
        int c0 = q * 8;
        int iy0 = oy * 2 - 1, ix0 = ox * 2 - 1;

        float sc[8], sh[8];
        #pragma unroll
        for (int ch = 0; ch < 8; ++ch) { sc[ch] = scL[c0 + ch]; sh[ch] = shL[c0 + ch]; }

        uint4 v[16];
        #pragma unroll
        for (int t = 0; t < 16; ++t) {
            int iy = iy0 + (t >> 2), ix = ix0 + (t & 3);
            int iyc = min(max(iy, 0), 63), ixc = min(max(ix, 0), 63);
            v[t] = *(const uint4*)&y1[((long)(b * 64 + iyc) * 64 + ixc) * 64 + c0];
        }
        float acc[8];
        #pragma unroll
        for (int ch = 0; ch < 8; ++ch) acc[ch] = 0.f;
        #pragma unroll
        for (int t = 0; t < 16; ++t) {
            int iy = iy0 + (t >> 2), ix = ix0 + (t & 3);
            bool ok = ((unsigned)iy < 64u) && ((unsigned)ix < 64u);
            float4 wa = *(const float4*)&klds[t * 64 + c0];
            float4 wb = *(const float4*)&klds[t * 64 + c0 + 4];
            const float wt[8] = {wa.x, wa.y, wa.z, wa.w, wb.x, wb.y, wb.z, wb.w};
            #pragma unroll
            for (int ch = 0; ch < 8; ++ch) {
                unsigned u = ((const unsigned*)&v[t])[ch >> 1];
                unsigned bits = (ch & 1) ? (u & 0xffff0000u) : (u << 16);
                float xb = ok ? fmaf(__uint_as_float(bits), sc[ch], sh[ch]) : 0.f;
                acc[ch] = fmaf(xb, wt[ch], acc[ch]);
            }
        }
        union { uint4 u4; unsigned short us[8]; } pk;
        #pragma unroll
        for (int ch = 0; ch < 8; ++ch) pk.us[ch] = f2b(acc[ch]);
        *(uint4*)&As[m * SK + q * 8] = pk.u4;
    }
    __syncthreads();

    floatx4 acc[4][4];
    #pragma unroll
    for (int i = 0; i < 4; ++i)
        #pragma unroll
        for (int j = 0; j < 4; ++j) acc[i][j] = (floatx4)0.0f;
    #pragma unroll
    for (int h = 0; h < 2; ++h) {
        short8 af[4], bfr[4];
        #pragma unroll
        for (int i = 0; i < 4; ++i) {
            af[i]  = *(const short8*)&As[(wm + i * 16 + lm) * SK + h * 32 + lq * 8];
            bfr[i] = *(const short8*)&Bs[(wn + i * 16 + lm) * SK + h * 32 + lq * 8];
        }
        #pragma unroll
        for (int i = 0; i < 4; ++i)
            #pragma unroll
            for (int j = 0; j < 4; ++j)
                acc[i][j] = __builtin_amdgcn_mfma_f32_16x16x32_bf16(af[i], bfr[j], acc[i][j], 0, 0, 0);
    }
    __syncthreads();

    float bj[4];
    #pragma unroll
    for (int j = 0; j < 4; ++j) bj[j] = bias[wn + j * 16 + lm];

    if (tid < 128) { sums[tid] = 0.f; sqs[tid] = 0.f; }
    #pragma unroll
    for (int i = 0; i < 4; ++i)
        #pragma unroll
        for (int j = 0; j < 4; ++j) {
            int c = wn + j * 16 + lm;
            #pragma unroll
            for (int rg = 0; rg < 4; ++rg) {
                int r = wm + i * 16 + lq * 4 + rg;
                float v = acc[i][j][rg] + bj[j];
                v = v > 0.f ? v : 0.2f * v;
                Csh[r * CS + c] = f2b(v);
            }
        }
    __syncthreads();
    {
        const int cg = tid & 15, mr = tid >> 4;
        float sacc[8], qacc[8];
        #pragma unroll
        for (int t = 0; t < 8; ++t) { sacc[t] = 0.f; qacc[t] = 0.f; }
        #pragma unroll
        for (int it = 0; it < 8; ++it) {
            int m = mr + it * 16;
            uint4 pk = *(const uint4*)&Csh[m * CS + cg * 8];
            *(uint4*)&y[(m0 + m) * 128 + cg * 8] = pk;
            const unsigned short* pu = (const unsigned short*)&pk;
            #pragma unroll
            for (int t = 0; t < 8; ++t) {
                float f = b2f(pu[t]);
                sacc[t] += f;
                qacc[t] = fmaf(f, f, qacc[t]);
            }
        }
        #pragma unroll
        for (int t = 0; t < 8; ++t) {
            atomicAdd(&sums[cg * 8 + t], sacc[t]);
            atomicAdd(&sqs [cg * 8 + t], qacc[t]);
        }
    }
    __syncthreads();
    {
        const int rep = blockIdx.x & (NREP - 1);
        if (tid < 128) {
            atomicAdd(&statsOut[rep * 256 + tid],        sums[tid]);
            atomicAdd(&statsOut[rep * 256 + 128 + tid],  sqs[tid]);
        }
    }
}

// ---------------------------------------------------------------------------
// Direct-tap depthwise conv (layers 3..5): thread = (output pixel, 8 ch).
// ---------------------------------------------------------------------------
template<int C, int KS, int HIN, int HOUT, int STRIDE, int PAD, int NTHR>
__global__ __launch_bounds__(NTHR) void dw_direct(
    const bf16* __restrict__ x, const float* __restrict__ aff,
    const float* __restrict__ dynkT, bf16* __restrict__ outA)
{
    constexpr int G   = C / 8;
    constexpr int KSK = KS * KS;
    static_assert(NTHR == HOUT * G, "one output row per block");

    __shared__ __align__(16) float wlds[KSK * C];

    const int tid = threadIdx.x;
    const int b   = blockIdx.x / HOUT;
    const int oy  = blockIdx.x % HOUT;

    {
        const float* src = dynkT + (long)b * (KSK * C);
        for (int i = tid * 4; i < KSK * C; i += NTHR * 4)
            *(float4*)&wlds[i] = *(const float4*)&src[i];
    }
    __syncthreads();

    const int g  = tid % G;
    const int ox = tid / G;
    const int c0 = g * 8;
    const int iy0 = oy * STRIDE - PAD;
    const int ix0 = ox * STRIDE - PAD;

    float sc[8], sh[8];
    {
        float4 a0 = *(const float4*)&aff[c0];
        float4 a1 = *(const float4*)&aff[c0 + 4];
        float4 b0 = *(const float4*)&aff[C + c0];
        float4 b1 = *(const float4*)&aff[C + c0 + 4];
        sc[0]=a0.x; sc[1]=a0.y; sc[2]=a0.z; sc[3]=a0.w;
        sc[4]=a1.x; sc[5]=a1.y; sc[6]=a1.z; sc[7]=a1.w;
        sh[0]=b0.x; sh[1]=b0.y; sh[2]=b0.z; sh[3]=b0.w;
        sh[4]=b1.x; sh[5]=b1.y; sh[6]=b1.z; sh[7]=b1.w;
    }

    float acc[8];
    #pragma unroll
    for (int ch = 0; ch < 8; ++ch) acc[ch] = 0.f;

    const bool interior = (iy0 >= 0) && (iy0 + KS <= HIN) &&
                          (ix0 >= 0) && (ix0 + KS <= HIN);

    if (interior) {
        const bf16* bp = x + ((long)(b * HIN + iy0) * HIN + ix0) * C + c0;
        uint4 v[KSK];
        #pragma unroll
        for (int kh = 0; kh < KS; ++kh)
            #pragma unroll
            for (int kw = 0; kw < KS; ++kw)
                v[kh * KS + kw] = *(const uint4*)(bp + (kh * HIN + kw) * C);
        #pragma unroll
        for (int t = 0; t < KSK; ++t) {
            const float* wp = &wlds[t * C + c0];
            float4 wa = *(const float4*)wp;
            float4 wb = *(const float4*)(wp + 4);
            const float wt[8] = {wa.x, wa.y, wa.z, wa.w, wb.x, wb.y, wb.z, wb.w};
            #pragma unroll
            for (int ch = 0; ch < 8; ++ch) {
                unsigned u = ((const unsigned*)&v[t])[ch >> 1];
                unsigned bits = (ch & 1) ? (u & 0xffff0000u) : (u << 16);
                float xb = fmaf(__uint_as_float(bits), sc[ch], sh[ch]);
                acc[ch] = fmaf(xb, wt[ch], acc[ch]);
            }
        }
    } else {
        #pragma unroll
        for (int kh = 0; kh < KS; ++kh) {
            const int iy = iy0 + kh;
            if ((unsigned)iy >= (unsigned)HIN) continue;
            #pragma unroll
            for (int kw = 0; kw < KS; ++kw) {
                const int ix = ix0 + kw;
                if ((unsigned)ix >= (unsigned)HIN) continue;
                uint4 v = *(const uint4*)&x[((long)(b * HIN + iy) * HIN + ix) * C + c0];
                const float* wp = &wlds[(kh * KS + kw) * C + c0];
                float4 wa = *(const float4*)wp;
                float4 wb = *(const float4*)(wp + 4);
                const float wt[8] = {wa.x, wa.y, wa.z, wa.w, wb.x, wb.y, wb.z, wb.w};
                #pragma unroll
                for (int ch = 0; ch < 8; ++ch) {
                    unsigned u = ((const unsigned*)&v)[ch >> 1];
                    unsigned bits = (ch & 1) ? (u & 0xffff0000u) : (u << 16);
                    float xb = fmaf(__uint_as_float(bits), sc[ch], sh[ch]);
                    acc[ch] = fmaf(xb, wt[ch], acc[ch]);
                }
            }
        }
    }

    union { uint4 v; unsigned short us[8]; } pk;
    #pragma unroll
    for (int ch = 0; ch < 8; ++ch) pk.us[ch] = f2b(acc[ch]);
    *(uint4*)&outA[((long)(b * HOUT + oy) * HOUT + ox) * C + c0] = pk.v;
}

// ---------------------------------------------------------------------------
// MFMA bf16 GEMM: C[M,COUT] = A[M,K] x W[K,COUT], 128x128 block tile, BK=64.
// ---------------------------------------------------------------------------
template<int K, int COUT, bool LAST>
__global__ __launch_bounds__(256) void gemm_layer(
    const bf16* __restrict__ A, const bf16* __restrict__ WT,
    const float* __restrict__ bias, bf16* __restrict__ y,
    float* __restrict__ statsOut, float* __restrict__ outF, int Mtiles)
{
    constexpr int SK = 72;
    constexpr int CS = 136;
    __shared__ __align__(16) unsigned short smem[18432];
    unsigned short* As  = smem;
    unsigned short* Bs  = smem + 9216;
    unsigned short* Csh = smem;
    __shared__ float sums[128], sqs[128];

    const int tid  = threadIdx.x;
    const int lane = tid & 63;
    const int w    = tid >> 6;
    const int wm   = (w >> 1) * 64, wn = (w & 1) * 64;
    const int lm   = lane & 15, lq = lane >> 4;
    const int mt   = blockIdx.x % Mtiles;
    const int nt   = blockIdx.x / Mtiles;
    const long m0  = (long)mt * 128;
    const int  n0  = nt * 128;

    floatx4 acc[4][4];
    #pragma unroll
    for (int i = 0; i < 4; ++i)
        #pragma unroll
        for (int j = 0; j < 4; ++j) acc[i][j] = (floatx4)0.0f;

    for (int kb = 0; kb < K; kb += 64) {
        __syncthreads();
        #pragma unroll
        for (int s = 0; s < 4; ++s) {
            int i = tid + s * 256;
            int m = i >> 3, q = i & 7;
            uint4 va = *(const uint4*)(A  + ((m0 + m) * K + kb + q * 8));
            uint4 vb = *(const uint4*)(WT + ((long)(n0 + m) * K + kb + q * 8));
            *(uint4*)&As[m * SK + q * 8] = va;
            *(uint4*)&Bs[m * SK + q * 8] = vb;
        }
        __syncthreads();
        #pragma unroll
        for (int h = 0; h < 2; ++h) {
            short8 af[4], bfr[4];
            #pragma unroll
            for (int i = 0; i < 4; ++i) {
                af[i]  = *(const short8*)&As[(wm + i * 16 + lm) * SK + h * 32 + lq * 8];
                bfr[i] = *(const short8*)&Bs[(wn + i * 16 + lm) * SK + h * 32 + lq * 8];
            }
            #pragma unroll
            for (int i = 0; i < 4; ++i)
                #pragma unroll
                for (int j = 0; j < 4; ++j)
                    acc[i][j] = __builtin_amdgcn_mfma_f32_16x16x32_bf16(af[i], bfr[j], acc[i][j], 0, 0, 0);
        }
    }
    __syncthreads();

    float bj[4];
    #pragma unroll
    for (int j = 0; j < 4; ++j) bj[j] = bias[n0 + wn + j * 16 + lm];

    if constexpr (!LAST) {
        if (tid < 128) { sums[tid] = 0.f; sqs[tid] = 0.f; }
        #pragma unroll
        for (int i = 0; i < 4; ++i)
            #pragma unroll
            for (int j = 0; j < 4; ++j) {
                int c = wn + j * 16 + lm;
                #pragma unroll
                for (int rg = 0; rg < 4; ++rg) {
                    int r = wm + i * 16 + lq * 4 + rg;
                    float v = acc[i][j][rg] + bj[j];
                    v = v > 0.f ? v : 0.2f * v;
                    Csh[r * CS + c] = f2b(v);
                }
            }
        __syncthreads();
        const int cg = tid & 15, mr = tid >> 4;
        float sacc[8], qacc[8];
        #pragma unroll
        for (int t = 0; t < 8; ++t) { sacc[t] = 0.f; qacc[t] = 0.f; }
        #pragma unroll
        for (int it = 0; it < 8; ++it) {
            int m = mr + it * 16;
            uint4 pk = *(const uint4*)&Csh[m * CS + cg * 8];
            *(uint4*)&y[(m0 + m) * COUT + n0 + cg * 8] = pk;
            const unsigned short* pu = (const unsigned short*)&pk;
            #pragma unroll
            for (int t = 0; t < 8; ++t) {
                float f = b2f(pu[t]);
                sacc[t] += f;
                qacc[t] = fmaf(f, f, qacc[t]);
            }
        }
        #pragma unroll
        for (int t = 0; t < 8; ++t) {
            atomicAdd(&sums[cg * 8 + t], sacc[t]);
            atomicAdd(&sqs [cg * 8 + t], qacc[t]);
        }
        __syncthreads();
        {
            const int rep = blockIdx.x & (NREP - 1);
            if (tid < 128) {
                atomicAdd(&statsOut[rep * 2 * COUT + n0 + tid],        sums[tid]);
                atomicAdd(&statsOut[rep * 2 * COUT + COUT + n0 + tid], sqs[tid]);
            }
        }
    } else {
        #pragma unroll
        for (int i = 0; i < 4; ++i)
            #pragma unroll
            for (int j = 0; j < 4; ++j) {
                int c  = wn + j * 16 + lm;
                int rb = wm + i * 16 + lq * 4;
                ushort4 pk;
                unsigned short* pp = (unsigned short*)&pk;
                #pragma unroll
                for (int rg = 0; rg < 4; ++rg)
                    pp[rg] = f2b(acc[i][j][rg] + bj[j]);
                *(ushort4*)&Csh[c * CS + rb] = pk;
            }
        __syncthreads();
        const int mg = tid & 15, nr = tid >> 4;
        #pragma unroll
        for (int it = 0; it < 8; ++it) {
            int n = nr + it * 16;
            uint4 pk = *(const uint4*)&Csh[n * CS + mg * 8];
            const unsigned short* pu = (const unsigned short*)&pk;
            #pragma unroll
            for (int t = 0; t < 8; ++t) {
                int m = (int)m0 + mg * 8 + t;
                int b = m / 49, pos = m - b * 49;
                float v = b2f(pu[t]);
                outF[((long)(b * 512 + n0 + n)) * 49 + pos] = 1.f / (1.f + __expf(-v));
            }
        }
    }
}

// ---------------------------------------------------------------------------

extern "C" void kernel_launch(void* const* d_in, const int* in_sizes, int n_in,
                              void* d_out, int out_size, void* d_ws, size_t ws_size,
                              hipStream_t stream)
{
    const float* input = (const float*)d_in[0];
    const int*   label = (const int*)d_in[1];
    const float* emb   = (const float*)d_in[2];
    const float* lw[5] = {(const float*)d_in[3], (const float*)d_in[5], (const float*)d_in[7],
                          (const float*)d_in[9], (const float*)d_in[11]};
    const float* lb[5] = {(const float*)d_in[4], (const float*)d_in[6], (const float*)d_in[8],
                          (const float*)d_in[10], (const float*)d_in[12]};
    const float* cmw[5] = {(const float*)d_in[13], (const float*)d_in[15], (const float*)d_in[17],
                           (const float*)d_in[19], (const float*)d_in[21]};
    const float* cmb[5] = {(const float*)d_in[14], (const float*)d_in[16], (const float*)d_in[18],
                           (const float*)d_in[20], (const float*)d_in[22]};
    const float* bng[4] = {(const float*)d_in[23], (const float*)d_in[25],
                           (const float*)d_in[27], (const float*)d_in[29]};
    const float* bnb[4] = {(const float*)d_in[24], (const float*)d_in[26],
                           (const float*)d_in[28], (const float*)d_in[30]};
    float* out = (float*)d_out;

    float* wsf   = (float*)d_ws;
    float* dynk  = wsf;
    float* stats = wsf + 1071104;
    const float* k1  = dynk;
    const float* k2T = dynk + 6144;
    const float* k3T = dynk + 137216;
    const float* k4T = dynk + 284672;
    const float* k5T = dynk + 808960;
    float* st1 = stats;
    float* st2 = stats + 2048;
    float* st3 = stats + 6144;
    float* st4 = stats + 14336;

    bf16* wt  = (bf16*)((char*)d_ws + 4407296);
    bf16* wt2 = wt;
    bf16* wt3 = wt + 8192;
    bf16* wt4 = wt + 40960;
    bf16* wt5 = wt + 172032;
    bf16* S1  = (bf16*)((char*)d_ws + 5308416);    // 33554432 elems capacity
    bf16* S2  = (bf16*)((char*)d_ws + 72417280);   // y2: 16777216 elems (33.5 MB)
    float* affBase = (float*)((char*)d_ws + 105971712);
    float* aff1 = affBase;          // 128
    float* aff2 = affBase + 128;    // 256
    float* aff3 = affBase + 384;    // 512
    float* aff4 = affBase + 896;    // 1024

    // S1 sub-regions for the L3..L5 chain (elems; y1 dead after gemm2_fused).
    // Sizes: A3 4194304 | y3 8388608 | A4 2097152 | y4 4194304 | A5 3211264.
    bf16* A3 = S1;                   // ends  4194304
    bf16* y3 = S1 + 4194304;         // ends 12582912
    bf16* A4 = S1 + 12582912;        // ends 14680064
    bf16* y4 = S1 + 14680064;        // ends 18874368
    bf16* A5 = S1 + 18874368;        // ends 22085632 < 33554432

    prep_kernel<<<4186, 256, 0, stream>>>(label, emb,
        lw[0], lb[0], lw[1], lb[1], lw[2], lb[2], lw[3], lb[3], lw[4], lb[4],
        dynk, stats, out + 3211264);
    wt_kernel<<<424, 256, 0, stream>>>(cmw[1], cmw[2], cmw[3], cmw[4],
                                       wt2, wt3, wt4, wt5);

    // L1: fused (K=3) -> y1 @ S1 + st1
    fused_l1_v6<<<2048, 256, 0, stream>>>(input, k1, cmw[0], cmb[0], S1, st1);

    // L2: dw fused into gemm A-staging; y1 (S1) -> y2 (S2)
    bn_prep<<<1, 64, 0, stream>>>(st1, bng[0], bnb[0], aff1, 64, 1.f / 524288.f);
    gemm2_fused<<<1024, 256, 0, stream>>>(S1, wt2, aff1, k2T, cmb[1], S2, st2);

    // L3: y2 (S2) -> A3 (S1) -> y3
    bn_prep<<<1, 128, 0, stream>>>(st2, bng[1], bnb[1], aff2, 128, 1.f / 131072.f);
    dw_direct<128, 3, 32, 16, 2, 1, 256><<<2048, 256, 0, stream>>>(S2, aff2, k3T, A3);
    gemm_layer<128, 256, false><<<512, 256, 0, stream>>>(
        A3, wt3, cmb[2], y3, st3, nullptr, 256);

    // L4: y3 -> A4 -> y4
    bn_prep<<<1, 256, 0, stream>>>(st3, bng[2], bnb[2], aff3, 256, 1.f / 32768.f);
    dw_direct<256, 4, 16, 8, 2, 1, 256><<<1024, 256, 0, stream>>>(y3, aff3, k4T, A4);
    gemm_layer<256, 512, false><<<256, 256, 0, stream>>>(
        A4, wt4, cmb[3], y4, st4, nullptr, 64);

    // L5: y4 -> A5 -> out
    bn_prep<<<1, 512, 0, stream>>>(st4, bng[3], bnb[3], aff4, 512, 1.f / 8192.f);
    dw_direct<512, 2, 8, 7, 1, 0, 448><<<896, 448, 0, stream>>>(y4, aff4, k5T, A5);
    gemm_layer<512, 512, true><<<196, 256, 0, stream>>>(
        A5, wt5, cmb[4], nullptr, nullptr, out, 49);
}